// Round 7
// baseline (285.694 us; speedup 1.0000x reference)
//
#include <hip/hip_runtime.h>
#include <hip/hip_bf16.h>

// ---------------------------------------------------------------------------
// CDAE forward. Round 7: item-centric CSR ratings.
// R6 post-mortem: k_ratings_bkt 40.8us with HBM 10%, VALU 22% -> bound by
// gather line throughput (2M row-gathers x 4 lines = 12.6cyc/gather/CU ~= L1
// line rate). Avg pairs/item = 10.5, so build exact per-item CSR (cap 48, one
// pass, 1M distributed atomics ~5us per R5's measured 212 atomics/ns) and make
// ratings item-centric: de_emb row+bias in registers ONCE per item, gather
// only hidden (1MB, L2-hot everywhere). Halves gather traffic. Scattered 4B
// stores into same-XCD L2 lines don't amplify (R4/R6 WRITE=4MB exact).
// Fusions: rowsort+fill+mask one dispatch; reg -> per-block partials, final
// reduce folded into unperm block 0. Dispatches 8 -> 6.
// Residual ~120us matches 3x41us harness ws-poison fills (WRITE=256MiB each,
// outside our control) -- this round tests that hypothesis via the residual.
// ---------------------------------------------------------------------------
#define PARTITIONABLE 1
#define FATB 2048          // fat grid for ratings
#define CAP 48             // per-item CSR capacity; E=10.5, P(Poisson>47)~1e-17
#define CAPR 128           // per-row capacity; E=50
#define RSB 200            // rowsort blocks: NNZ=204800 = 200 * 4 * 256
#define FILLB 1024         // fill blocks in fused prep kernel
#define REGB 256           // reg partial blocks

__device__ __forceinline__ unsigned rotl32(unsigned x, int r) {
    return (x << r) | (x >> (32 - r));
}

__device__ __forceinline__ void threefry2x32(unsigned k0, unsigned k1,
                                             unsigned& x0, unsigned& x1) {
    unsigned ks0 = k0, ks1 = k1, ks2 = k0 ^ k1 ^ 0x1BD11BDAu;
    x0 += ks0; x1 += ks1;
#define TF_R(r) { x0 += x1; x1 = rotl32(x1, r); x1 ^= x0; }
    TF_R(13) TF_R(15) TF_R(26) TF_R(6)   x0 += ks1; x1 += ks2 + 1u;
    TF_R(17) TF_R(29) TF_R(16) TF_R(24)  x0 += ks2; x1 += ks0 + 2u;
    TF_R(13) TF_R(15) TF_R(26) TF_R(6)   x0 += ks0; x1 += ks1 + 3u;
    TF_R(17) TF_R(29) TF_R(16) TF_R(24)  x0 += ks1; x1 += ks2 + 4u;
    TF_R(13) TF_R(15) TF_R(26) TF_R(6)   x0 += ks2; x1 += ks0 + 5u;
#undef TF_R
}

__device__ __forceinline__ bool keep_mask(int i, int nnz) {
#if PARTITIONABLE
    unsigned x0 = 0u, x1 = (unsigned)i;
    threefry2x32(0u, 42u, x0, x1);
    unsigned bits = x0 ^ x1;
#else
    int half = nnz >> 1;
    int j = (i < half) ? i : i - half;
    unsigned x0 = (unsigned)j, x1 = (unsigned)(j + half);
    threefry2x32(0u, 42u, x0, x1);
    unsigned bits = (i < half) ? x0 : x1;
#endif
    float u = __uint_as_float((bits >> 9) | 0x3f800000u) - 1.0f;
    return u < 0.8f;
}

// ===================== fused prep: rowsort (blocks<RSB) + CSR fill ==========
__global__ void k_prep(const int* __restrict__ sp_row, const int* __restrict__ sp_col,
                       int* __restrict__ rowcur, unsigned* __restrict__ srow,
                       const int* __restrict__ bat_idx, const int* __restrict__ bat_items,
                       unsigned char* __restrict__ mask, int* __restrict__ cnt,
                       unsigned* __restrict__ payload, unsigned* __restrict__ inv,
                       int nnz, int B, int N) {
    if (blockIdx.x < RSB) {
        // ---- nnz counting-sort by row; payload col<<1|keep ----
        __shared__ int h[4096];
        for (int i = threadIdx.x; i < B; i += blockDim.x) h[i] = 0;
        __syncthreads();
        const int per = nnz / RSB;                 // 1024
        const int base = blockIdx.x * per;
        const int iters = per / blockDim.x;        // 4
        unsigned pk[8];
        int rw[8];
        for (int it = 0; it < iters; ++it) {
            int i = base + it * blockDim.x + threadIdx.x;
            int row = sp_row[i];
            int col = sp_col[i];
            unsigned k = keep_mask(i, nnz) ? 1u : 0u;
            pk[it] = ((unsigned)col << 1) | k;
            rw[it] = row;
            atomicAdd(&h[row], 1);
        }
        __syncthreads();
        for (int i = threadIdx.x; i < B; i += blockDim.x) {
            int c = h[i];
            if (c) h[i] = atomicAdd(&rowcur[i], c);
        }
        __syncthreads();
        for (int it = 0; it < iters; ++it) {
            int row = rw[it];
            int pos = atomicAdd(&h[row], 1);
            srow[(size_t)row * CAPR + min(pos, CAPR - 1)] = pk[it];
        }
    } else {
        // ---- per-item CSR fill + mask; payload n<<12|bidx ----
        const int stride = FILLB * blockDim.x;
        for (int n = (int)(blockIdx.x - RSB) * blockDim.x + threadIdx.x; n < N; n += stride) {
            int item = bat_items[n];
            int bidx = bat_idx[n];
            mask[item] = 1;
            int pos = atomicAdd(&cnt[item], 1);
            unsigned gp = (unsigned)item * CAP + (unsigned)min(pos, CAP - 1);
            payload[gp] = ((unsigned)n << 12) | (unsigned)bidx;
            inv[n] = gp;
        }
    }
}

// ===================== hidden: one wave per row, register accumulate ========
__global__ void k_hidden(const unsigned* __restrict__ srow, const int* __restrict__ rowcur,
                         const float* __restrict__ en_emb, const float* __restrict__ user_emb,
                         const int* __restrict__ user_ids, const float* __restrict__ en_off,
                         float* __restrict__ hidden, int B) {
    const int lane = threadIdx.x & 63;
    const int row = (blockIdx.x * blockDim.x + threadIdx.x) >> 6;
    if (row >= B) return;
    const int cnt = min(rowcur[row], CAPR);
    const unsigned* sr = srow + (size_t)row * CAPR;
    float acc0 = 0.f, acc1 = 0.f;
    for (int j0 = 0; j0 < cnt; j0 += 64) {
        unsigned ev = (j0 + lane < cnt) ? sr[j0 + lane] : 0u;
        int m = min(64, cnt - j0);
        int jj = 0;
        for (; jj + 1 < m; jj += 2) {
            unsigned e0 = __shfl(ev, jj);
            unsigned e1 = __shfl(ev, jj + 1);
            if (e0 & 1u) acc0 += en_emb[(size_t)(e0 >> 1) * 64 + lane];
            if (e1 & 1u) acc1 += en_emb[(size_t)(e1 >> 1) * 64 + lane];
        }
        if (jj < m) {
            unsigned e0 = __shfl(ev, jj);
            if (e0 & 1u) acc0 += en_emb[(size_t)(e0 >> 1) * 64 + lane];
        }
    }
    int uid = user_ids[row];
    float hval = 1.25f * (acc0 + acc1) + user_emb[(size_t)uid * 64 + lane] + en_off[lane];
    hidden[(size_t)row * 64 + lane] = tanhf(hval);
}

// ===================== ratings: item-centric, de_emb row in registers =======
__global__ void k_ratings_item(const float* __restrict__ hidden, const float* __restrict__ de_emb,
                               const float* __restrict__ de_bias, const int* __restrict__ cnt,
                               const unsigned* __restrict__ payload, float* __restrict__ r,
                               int num_items) {
    const int l = threadIdx.x & 15;
    const int g = (blockIdx.x * blockDim.x + threadIdx.x) >> 4;
    const int G = (gridDim.x * blockDim.x) >> 4;
    for (int item = g; item < num_items; item += G) {
        int c = min(cnt[item], CAP);
        if (c == 0) continue;
        float4 dv = *reinterpret_cast<const float4*>(de_emb + (size_t)item * 64 + l * 4);
        float bias = de_bias[item];
        const unsigned* pl = payload + (size_t)item * CAP;
        float* rr = r + (size_t)item * CAP;
        int j = 0;
        for (; j + 1 < c; j += 2) {                 // 2 independent gather chains
            unsigned p0 = pl[j], p1 = pl[j + 1];
            int b0 = (int)(p0 & 0xFFFu), b1 = (int)(p1 & 0xFFFu);
            float4 h0 = *reinterpret_cast<const float4*>(hidden + (size_t)b0 * 64 + l * 4);
            float4 h1 = *reinterpret_cast<const float4*>(hidden + (size_t)b1 * 64 + l * 4);
            float s0 = h0.x*dv.x + h0.y*dv.y + h0.z*dv.z + h0.w*dv.w;
            float s1 = h1.x*dv.x + h1.y*dv.y + h1.z*dv.z + h1.w*dv.w;
            s0 += __shfl_xor(s0, 1); s1 += __shfl_xor(s1, 1);
            s0 += __shfl_xor(s0, 2); s1 += __shfl_xor(s1, 2);
            s0 += __shfl_xor(s0, 4); s1 += __shfl_xor(s1, 4);
            s0 += __shfl_xor(s0, 8); s1 += __shfl_xor(s1, 8);
            if (l == 0) { rr[j] = s0 + bias; rr[j + 1] = s1 + bias; }
        }
        if (j < c) {
            unsigned p0 = pl[j];
            int b0 = (int)(p0 & 0xFFFu);
            float4 h0 = *reinterpret_cast<const float4*>(hidden + (size_t)b0 * 64 + l * 4);
            float s0 = h0.x*dv.x + h0.y*dv.y + h0.z*dv.z + h0.w*dv.w;
            s0 += __shfl_xor(s0, 1);
            s0 += __shfl_xor(s0, 2);
            s0 += __shfl_xor(s0, 4);
            s0 += __shfl_xor(s0, 8);
            if (l == 0) rr[j] = s0 + bias;
        }
    }
}

// ===================== reg: per-block partials (no memset, no atomics) ======
__global__ void k_reg_part(const unsigned char* __restrict__ mask,
                           const float* __restrict__ en_emb, const float* __restrict__ de_emb,
                           const float* __restrict__ de_bias,
                           const float* __restrict__ user_emb, const int* __restrict__ user_ids,
                           const float* __restrict__ en_off,
                           float* __restrict__ partials, int num_items, int B) {
    const int stride = gridDim.x * blockDim.x;
    float s = 0.f;
    for (int t = blockIdx.x * blockDim.x + threadIdx.x; t < num_items * 16; t += stride) {
        int i = t >> 4, l = t & 15;
        if (mask[i]) {
            float4 e = *reinterpret_cast<const float4*>(en_emb + (size_t)i * 64 + l * 4);
            float4 d = *reinterpret_cast<const float4*>(de_emb + (size_t)i * 64 + l * 4);
            s += e.x*e.x + e.y*e.y + e.z*e.z + e.w*e.w
               + d.x*d.x + d.y*d.y + d.z*d.z + d.w*d.w;
            if (l == 0) { float bb = de_bias[i]; s += bb * bb; }
        }
    }
    for (int t = blockIdx.x * blockDim.x + threadIdx.x; t < B * 16; t += stride) {
        int b = t >> 4, l = t & 15;
        int uid = user_ids[b];
        float4 u = *reinterpret_cast<const float4*>(user_emb + (size_t)uid * 64 + l * 4);
        s += u.x*u.x + u.y*u.y + u.z*u.z + u.w*u.w;
    }
    if (blockIdx.x == 0 && threadIdx.x < 64) {
        float o = en_off[threadIdx.x];
        s += o * o;
    }
    for (int m = 1; m < 64; m <<= 1) s += __shfl_xor(s, m);
    __shared__ float wsum[4];
    if ((threadIdx.x & 63) == 0) wsum[threadIdx.x >> 6] = s;
    __syncthreads();
    if (threadIdx.x == 0)
        partials[blockIdx.x] = wsum[0] + wsum[1] + wsum[2] + wsum[3];
}

// ===================== unpermute + final reg reduce =========================
__global__ void k_unperm(const unsigned* __restrict__ inv, const float* __restrict__ r,
                         const float* __restrict__ partials,
                         float* __restrict__ out, int N) {
    const int stride = gridDim.x * blockDim.x;
    for (int t = blockIdx.x * blockDim.x + threadIdx.x; t < N; t += stride)
        out[t] = r[inv[t]];
    if (blockIdx.x == 0 && threadIdx.x < 64) {
        float s = 0.f;
        for (int i = threadIdx.x; i < REGB; i += 64) s += partials[i];
        for (int m = 1; m < 64; m <<= 1) s += __shfl_xor(s, m);
        if (threadIdx.x == 0) out[N] = 0.5f * s;
    }
}

// ===================== fallback (direct) path ===============================
__global__ void k_mask(const int* __restrict__ bat_items, unsigned char* __restrict__ mask,
                       int N) {
    int t = blockIdx.x * blockDim.x + threadIdx.x;
    if (t < N) mask[bat_items[t]] = 1;
}

__global__ void k_ratings(const float* __restrict__ hidden, const float* __restrict__ de_emb,
                          const float* __restrict__ de_bias,
                          const int* __restrict__ bat_idx, const int* __restrict__ bat_items,
                          float* __restrict__ out, int N) {
    const int l = threadIdx.x & 15;
    const int gid = (blockIdx.x * blockDim.x + threadIdx.x) >> 4;
    const int gstride = (gridDim.x * blockDim.x) >> 4;
    for (int n = gid; n < N; n += gstride) {
        int b  = bat_idx[n];
        int it = bat_items[n];
        float4 hv = *reinterpret_cast<const float4*>(hidden + (size_t)b  * 64 + l * 4);
        float4 dv = *reinterpret_cast<const float4*>(de_emb + (size_t)it * 64 + l * 4);
        float s = hv.x*dv.x + hv.y*dv.y + hv.z*dv.z + hv.w*dv.w;
        s += __shfl_xor(s, 1);
        s += __shfl_xor(s, 2);
        s += __shfl_xor(s, 4);
        s += __shfl_xor(s, 8);
        if (l == 0) out[n] = s + de_bias[it];
    }
}

__global__ void k_scatter(const int* __restrict__ sp_row, const int* __restrict__ sp_col,
                          const float* __restrict__ en_emb, float* __restrict__ hidden,
                          int nnz) {
    const int lane = threadIdx.x & 63;
    const int wave = (blockIdx.x * blockDim.x + threadIdx.x) >> 6;
    const int nwaves = (gridDim.x * blockDim.x) >> 6;
    for (int i = wave; i < nnz; i += nwaves) {
        if (!keep_mask(i, nnz)) continue;
        int row = sp_row[i];
        int col = sp_col[i];
        float v = 1.25f * en_emb[(size_t)col * 64 + lane];
        atomicAdd(&hidden[row * 64 + lane], v);
    }
}

__global__ void k_hfinish(float* __restrict__ hidden, const float* __restrict__ user_emb,
                          const int* __restrict__ user_ids, const float* __restrict__ en_off,
                          int B) {
    int t = blockIdx.x * blockDim.x + threadIdx.x;
    if (t >= B * 64) return;
    int b = t >> 6, d = t & 63;
    int uid = user_ids[b];
    float h = hidden[t] + user_emb[(size_t)uid * 64 + d] + en_off[d];
    hidden[t] = tanhf(h);
}

__global__ void k_final_fb(const float* __restrict__ partials, float* __restrict__ out, int N) {
    if (threadIdx.x < 64) {
        float s = 0.f;
        for (int i = threadIdx.x; i < REGB; i += 64) s += partials[i];
        for (int m = 1; m < 64; m <<= 1) s += __shfl_xor(s, m);
        if (threadIdx.x == 0) out[N] = 0.5f * s;
    }
}

extern "C" void kernel_launch(void* const* d_in, const int* in_sizes, int n_in,
                              void* d_out, int out_size, void* d_ws, size_t ws_size,
                              hipStream_t stream) {
    const int*   user_ids  = (const int*)  d_in[0];
    const int*   bat_idx   = (const int*)  d_in[1];
    const int*   sp_row    = (const int*)  d_in[2];
    const int*   sp_col    = (const int*)  d_in[3];
    const int*   bat_items = (const int*)  d_in[4];
    const float* en_emb    = (const float*)d_in[5];
    const float* en_off    = (const float*)d_in[6];
    const float* de_emb    = (const float*)d_in[7];
    const float* de_bias   = (const float*)d_in[8];
    const float* user_emb  = (const float*)d_in[9];

    const int B         = in_sizes[0];
    const int N         = in_sizes[1];
    const int NNZ       = in_sizes[2];
    const int NUM_ITEMS = in_sizes[8];

    float* out = (float*)d_out;        // ratings [N] ; reg scalar at out[N]

    // workspace: [mask | cnt | rowcur] one memset; rest uninitialized-ok.
    char* ws = (char*)d_ws;
    size_t off = 0;
    unsigned char* mask = (unsigned char*)(ws + off);
    off += ((size_t)NUM_ITEMS + 255) & ~(size_t)255;
    int* cnt    = (int*)(ws + off);               off += (size_t)NUM_ITEMS * 4;
    int* rowcur = (int*)(ws + off);               off += (size_t)B * 4;
    const size_t zero_bytes = off;
    float* hidden = (float*)(ws + off);           off += (size_t)B * 64 * 4;
    unsigned* payload = (unsigned*)(ws + off);    off += (size_t)NUM_ITEMS * CAP * 4;
    unsigned* inv     = (unsigned*)(ws + off);    off += (size_t)N * 4;
    float*    r       = (float*)(ws + off);
    unsigned* srow    = (unsigned*)r;             // alias: disjoint lifetimes
    size_t tail = (size_t)NUM_ITEMS * CAP * 4;
    if ((size_t)B * CAPR * 4 > tail) tail = (size_t)B * CAPR * 4;
    off += tail;
    float* partials = (float*)(ws + off);         off += REGB * 4;

    const bool fast_path =
        (ws_size >= off) && (N == (1 << 20)) && (B == 4096) &&
        (NUM_ITEMS <= (1 << 17)) && (NNZ % (RSB * 256) == 0) &&
        (NNZ / RSB <= CAPR * 256);

    if (fast_path) {
        hipMemsetAsync(ws, 0, zero_bytes, stream);
        k_prep<<<RSB + FILLB, 256, 0, stream>>>(sp_row, sp_col, rowcur, srow,
                                                bat_idx, bat_items, mask, cnt,
                                                payload, inv, NNZ, B, N);
        k_hidden<<<(B * 64 + 255) / 256, 256, 0, stream>>>(
            srow, rowcur, en_emb, user_emb, user_ids, en_off, hidden, B);
        k_ratings_item<<<FATB, 256, 0, stream>>>(hidden, de_emb, de_bias, cnt,
                                                 payload, r, NUM_ITEMS);
        k_reg_part<<<REGB, 256, 0, stream>>>(mask, en_emb, de_emb, de_bias,
                                             user_emb, user_ids, en_off,
                                             partials, NUM_ITEMS, B);
        k_unperm<<<1024, 256, 0, stream>>>(inv, r, partials, out, N);
    } else {
        hipMemsetAsync(ws, 0, zero_bytes, stream);
        hipMemsetAsync(hidden, 0, (size_t)B * 64 * 4, stream);
        k_mask<<<(N + 255) / 256, 256, 0, stream>>>(bat_items, mask, N);
        k_scatter<<<FATB, 256, 0, stream>>>(sp_row, sp_col, en_emb, hidden, NNZ);
        k_hfinish<<<(B * 64 + 255) / 256, 256, 0, stream>>>(hidden, user_emb, user_ids,
                                                            en_off, B);
        k_ratings<<<FATB, 256, 0, stream>>>(hidden, de_emb, de_bias, bat_idx, bat_items, out, N);
        k_reg_part<<<REGB, 256, 0, stream>>>(mask, en_emb, de_emb, de_bias,
                                             user_emb, user_ids, en_off,
                                             partials, NUM_ITEMS, B);
        k_final_fb<<<1, 64, 0, stream>>>(partials, out, N);
    }
}

// Round 8
// 234.925 us; speedup vs baseline: 1.2161x; 1.2161x over previous
//
#include <hip/hip_runtime.h>
#include <hip/hip_bf16.h>

// ---------------------------------------------------------------------------
// CDAE forward. Round 8: revert to R6 pipeline + bf16-compressed ratings.
// R7 post-mortem: item-CSR fill scattered 1M x 4B payload stores over 19.2MB
// -> 75MB WRITE (full-line dirtying + RMW fills), k_prep 70us. Global scatter
// stores are poison (~1TB/s effective); R6's bucket writes (contiguous 2KB
// runs) are the right structure. REVERT to R6.
// New: ratings is line-throughput bound (1M pairs x 8 cache lines). Halve it:
// hidden stored bf16 (2 lines/row) and de_emb converted to bf16 (2 lines/row,
// 12.8MB -> smaller L2 slice) -- cvt fused as extra blocks of the k_bucket
// dispatch. bf16 = truncated fp32, decode is shift/and; accumulate fp32.
// Fixed ~120us of harness 0xAA ws-poison fills (3x41us, WRITE=256MiB each) is
// outside our control; controllable R6 budget was ~115us, ratings 40.8us.
// ---------------------------------------------------------------------------
#define PARTITIONABLE 1
#define NB 8               // item-slice buckets == XCDs (blockIdx&7 pinning)
#define CAPB 136192        // per-item-bucket capacity; E=131072, +14 sigma
#define FATB 2048          // fat grid size for ratings
#define CAPR 128           // per-row capacity; E=50
#define RSB 200            // rowsort blocks: NNZ=204800 = 200 * 4 * 256
#define CVTB 512           // de_emb fp32->bf16 cvt blocks (fused in k_bucket)

__device__ __forceinline__ unsigned rotl32(unsigned x, int r) {
    return (x << r) | (x >> (32 - r));
}

__device__ __forceinline__ void threefry2x32(unsigned k0, unsigned k1,
                                             unsigned& x0, unsigned& x1) {
    unsigned ks0 = k0, ks1 = k1, ks2 = k0 ^ k1 ^ 0x1BD11BDAu;
    x0 += ks0; x1 += ks1;
#define TF_R(r) { x0 += x1; x1 = rotl32(x1, r); x1 ^= x0; }
    TF_R(13) TF_R(15) TF_R(26) TF_R(6)   x0 += ks1; x1 += ks2 + 1u;
    TF_R(17) TF_R(29) TF_R(16) TF_R(24)  x0 += ks2; x1 += ks0 + 2u;
    TF_R(13) TF_R(15) TF_R(26) TF_R(6)   x0 += ks0; x1 += ks1 + 3u;
    TF_R(17) TF_R(29) TF_R(16) TF_R(24)  x0 += ks1; x1 += ks2 + 4u;
    TF_R(13) TF_R(15) TF_R(26) TF_R(6)   x0 += ks2; x1 += ks0 + 5u;
#undef TF_R
}

__device__ __forceinline__ bool keep_mask(int i, int nnz) {
#if PARTITIONABLE
    unsigned x0 = 0u, x1 = (unsigned)i;
    threefry2x32(0u, 42u, x0, x1);
    unsigned bits = x0 ^ x1;
#else
    int half = nnz >> 1;
    int j = (i < half) ? i : i - half;
    unsigned x0 = (unsigned)j, x1 = (unsigned)(j + half);
    threefry2x32(0u, 42u, x0, x1);
    unsigned bits = (i < half) ? x0 : x1;
#endif
    float u = __uint_as_float((bits >> 9) | 0x3f800000u) - 1.0f;
    return u < 0.8f;
}

// fp32 -> bf16 round-to-nearest-even
__device__ __forceinline__ unsigned short f2bf(float f) {
    unsigned u = __float_as_uint(f);
    return (unsigned short)((u + 0x7FFFu + ((u >> 16) & 1u)) >> 16);
}

// dot of 4 bf16 pairs packed in uint2 (lo half = even element), fp32 accum
__device__ __forceinline__ float bfdot4(uint2 h, uint2 d) {
    float s;
    s  = __uint_as_float(h.x << 16)         * __uint_as_float(d.x << 16);
    s += __uint_as_float(h.x & 0xFFFF0000u) * __uint_as_float(d.x & 0xFFFF0000u);
    s += __uint_as_float(h.y << 16)         * __uint_as_float(d.y << 16);
    s += __uint_as_float(h.y & 0xFFFF0000u) * __uint_as_float(d.y & 0xFFFF0000u);
    return s;
}

// ========== pair bucketing by item slice (blocks<256) + de_emb cvt =========
__global__ void k_bucket(const int* __restrict__ bat_idx, const int* __restrict__ bat_items,
                         unsigned char* __restrict__ mask, int* __restrict__ cursor,
                         unsigned* __restrict__ perm, unsigned* __restrict__ inv,
                         const float* __restrict__ de_emb, unsigned short* __restrict__ debf,
                         int N, int num_items) {
    if (blockIdx.x < 256) {
        __shared__ int h[NB];
        if (threadIdx.x < NB) h[threadIdx.x] = 0;
        __syncthreads();
        const int per = N / 256;                       // 4096
        const int base_n = blockIdx.x * per;
        const int iters = per / blockDim.x;            // 16
        unsigned packed[16];
        int bkt[16];
        for (int it = 0; it < iters; ++it) {
            int n = base_n + it * blockDim.x + threadIdx.x;
            int item = bat_items[n];
            int bidx = bat_idx[n];
            mask[item] = 1;
            int b = (int)(((unsigned long long)(unsigned)item * NB) / (unsigned)num_items);
            packed[it] = ((unsigned)item << 12) | (unsigned)bidx;   // item:17 | bidx:12
            bkt[it] = b;
            atomicAdd(&h[b], 1);
        }
        __syncthreads();
        if (threadIdx.x < NB) {
            int c = h[threadIdx.x];
            h[threadIdx.x] = atomicAdd(&cursor[threadIdx.x], c);
        }
        __syncthreads();
        for (int it = 0; it < iters; ++it) {
            int n = base_n + it * blockDim.x + threadIdx.x;
            int b = bkt[it];
            int pos = atomicAdd(&h[b], 1);
            unsigned gpos = (unsigned)b * CAPB + (unsigned)min(pos, CAPB - 1);
            perm[gpos] = packed[it];   // contiguous per-(block,bucket) runs
            inv[n] = gpos;
        }
    } else {
        // ---- de_emb fp32 -> bf16, coalesced stream (quads of 4 floats) ----
        const int quads = num_items * 16;
        const int stride = CVTB * blockDim.x;
        for (int q = (int)(blockIdx.x - 256) * blockDim.x + threadIdx.x; q < quads;
             q += stride) {
            float4 v = reinterpret_cast<const float4*>(de_emb)[q];
            ushort4 o;
            o.x = f2bf(v.x); o.y = f2bf(v.y); o.z = f2bf(v.z); o.w = f2bf(v.w);
            reinterpret_cast<ushort4*>(debf)[q] = o;
        }
    }
}

// ===================== nnz counting-sort by row =============================
__global__ void k_rowsort(const int* __restrict__ sp_row, const int* __restrict__ sp_col,
                          int* __restrict__ rowcur, unsigned* __restrict__ srow,
                          int nnz, int B) {
    __shared__ int h[4096];
    for (int i = threadIdx.x; i < B; i += blockDim.x) h[i] = 0;
    __syncthreads();
    const int per = nnz / gridDim.x;               // 1024
    const int base = blockIdx.x * per;
    const int iters = per / blockDim.x;            // 4
    unsigned pk[8];
    int rw[8];
    for (int it = 0; it < iters; ++it) {
        int i = base + it * blockDim.x + threadIdx.x;
        int row = sp_row[i];
        int col = sp_col[i];
        unsigned k = keep_mask(i, nnz) ? 1u : 0u;
        pk[it] = ((unsigned)col << 1) | k;
        rw[it] = row;
        atomicAdd(&h[row], 1);
    }
    __syncthreads();
    for (int i = threadIdx.x; i < B; i += blockDim.x) {
        int c = h[i];
        if (c) h[i] = atomicAdd(&rowcur[i], c);
    }
    __syncthreads();
    for (int it = 0; it < iters; ++it) {
        int row = rw[it];
        int pos = atomicAdd(&h[row], 1);
        srow[(size_t)row * CAPR + min(pos, CAPR - 1)] = pk[it];
    }
}

// ========== hidden: one wave per row, register accumulate, bf16 store ======
__global__ void k_hidden(const unsigned* __restrict__ srow, const int* __restrict__ rowcur,
                         const float* __restrict__ en_emb, const float* __restrict__ user_emb,
                         const int* __restrict__ user_ids, const float* __restrict__ en_off,
                         unsigned short* __restrict__ hb, int B) {
    const int lane = threadIdx.x & 63;
    const int row = (blockIdx.x * blockDim.x + threadIdx.x) >> 6;
    if (row >= B) return;
    const int cnt = min(rowcur[row], CAPR);
    const unsigned* sr = srow + (size_t)row * CAPR;
    float acc0 = 0.f, acc1 = 0.f;
    for (int j0 = 0; j0 < cnt; j0 += 64) {
        unsigned ev = (j0 + lane < cnt) ? sr[j0 + lane] : 0u;
        int m = min(64, cnt - j0);
        int jj = 0;
        for (; jj + 1 < m; jj += 2) {
            unsigned e0 = __shfl(ev, jj);
            unsigned e1 = __shfl(ev, jj + 1);
            if (e0 & 1u) acc0 += en_emb[(size_t)(e0 >> 1) * 64 + lane];
            if (e1 & 1u) acc1 += en_emb[(size_t)(e1 >> 1) * 64 + lane];
        }
        if (jj < m) {
            unsigned e0 = __shfl(ev, jj);
            if (e0 & 1u) acc0 += en_emb[(size_t)(e0 >> 1) * 64 + lane];
        }
    }
    int uid = user_ids[row];
    float hval = 1.25f * (acc0 + acc1) + user_emb[(size_t)uid * 64 + lane] + en_off[lane];
    hb[(size_t)row * 64 + lane] = f2bf(tanhf(hval));
}

// ========== ratings: bf16 gathers, fat grid-stride, XCD-pinned buckets =====
__global__ void k_ratings_bkt(const unsigned short* __restrict__ hb,
                              const unsigned short* __restrict__ debf,
                              const float* __restrict__ de_bias,
                              const unsigned* __restrict__ perm, const int* __restrict__ cursor,
                              float* __restrict__ r_perm) {
    const int bkt = blockIdx.x & (NB - 1);
    const int cnt = cursor[bkt];
    const int l = threadIdx.x & 15;
    const int gid = (blockIdx.x >> 3) * (blockDim.x >> 4) + (threadIdx.x >> 4);
    const int gpb = (gridDim.x >> 3) * (blockDim.x >> 4);
    const unsigned* pb = perm + (size_t)bkt * CAPB;
    float* rb = r_perm + (size_t)bkt * CAPB;

    int slot = gid;
    for (; slot + gpb < cnt; slot += 2 * gpb) {
        unsigned p0 = pb[slot];
        unsigned p1 = pb[slot + gpb];
        int it0 = (int)(p0 >> 12), b0 = (int)(p0 & 0xFFFu);
        int it1 = (int)(p1 >> 12), b1 = (int)(p1 & 0xFFFu);
        uint2 h0 = *reinterpret_cast<const uint2*>(hb   + (size_t)b0  * 64 + l * 4);
        uint2 d0 = *reinterpret_cast<const uint2*>(debf + (size_t)it0 * 64 + l * 4);
        uint2 h1 = *reinterpret_cast<const uint2*>(hb   + (size_t)b1  * 64 + l * 4);
        uint2 d1 = *reinterpret_cast<const uint2*>(debf + (size_t)it1 * 64 + l * 4);
        float s0 = bfdot4(h0, d0);
        float s1 = bfdot4(h1, d1);
        s0 += __shfl_xor(s0, 1); s1 += __shfl_xor(s1, 1);
        s0 += __shfl_xor(s0, 2); s1 += __shfl_xor(s1, 2);
        s0 += __shfl_xor(s0, 4); s1 += __shfl_xor(s1, 4);
        s0 += __shfl_xor(s0, 8); s1 += __shfl_xor(s1, 8);
        if (l == 0) {
            rb[slot]       = s0 + de_bias[it0];
            rb[slot + gpb] = s1 + de_bias[it1];
        }
    }
    for (; slot < cnt; slot += gpb) {
        unsigned p = pb[slot];
        int item = (int)(p >> 12), bidx = (int)(p & 0xFFFu);
        uint2 hv = *reinterpret_cast<const uint2*>(hb   + (size_t)bidx * 64 + l * 4);
        uint2 dv = *reinterpret_cast<const uint2*>(debf + (size_t)item * 64 + l * 4);
        float s = bfdot4(hv, dv);
        s += __shfl_xor(s, 1);
        s += __shfl_xor(s, 2);
        s += __shfl_xor(s, 4);
        s += __shfl_xor(s, 8);
        if (l == 0) rb[slot] = s + de_bias[item];
    }
}

// ===================== unpermute: gather, coalesced stores ==================
__global__ void k_unperm(const unsigned* __restrict__ inv, const float* __restrict__ r_perm,
                         float* __restrict__ out, int N) {
    const int stride = gridDim.x * blockDim.x;
    for (int t = blockIdx.x * blockDim.x + threadIdx.x; t < N; t += stride)
        out[t] = r_perm[inv[t]];
}

// ===================== fallback (direct) path ===============================
__global__ void k_mask(const int* __restrict__ bat_items, unsigned char* __restrict__ mask,
                       int N) {
    int t = blockIdx.x * blockDim.x + threadIdx.x;
    if (t < N) mask[bat_items[t]] = 1;
}

__global__ void k_ratings(const float* __restrict__ hidden, const float* __restrict__ de_emb,
                          const float* __restrict__ de_bias,
                          const int* __restrict__ bat_idx, const int* __restrict__ bat_items,
                          float* __restrict__ out, int N) {
    const int l = threadIdx.x & 15;
    const int gid = (blockIdx.x * blockDim.x + threadIdx.x) >> 4;
    const int gstride = (gridDim.x * blockDim.x) >> 4;
    for (int n = gid; n < N; n += gstride) {
        int b  = bat_idx[n];
        int it = bat_items[n];
        float4 hv = *reinterpret_cast<const float4*>(hidden + (size_t)b  * 64 + l * 4);
        float4 dv = *reinterpret_cast<const float4*>(de_emb + (size_t)it * 64 + l * 4);
        float s = hv.x*dv.x + hv.y*dv.y + hv.z*dv.z + hv.w*dv.w;
        s += __shfl_xor(s, 1);
        s += __shfl_xor(s, 2);
        s += __shfl_xor(s, 4);
        s += __shfl_xor(s, 8);
        if (l == 0) out[n] = s + de_bias[it];
    }
}

__global__ void k_scatter(const int* __restrict__ sp_row, const int* __restrict__ sp_col,
                          const float* __restrict__ en_emb, float* __restrict__ hidden,
                          int nnz) {
    const int lane = threadIdx.x & 63;
    const int wave = (blockIdx.x * blockDim.x + threadIdx.x) >> 6;
    const int nwaves = (gridDim.x * blockDim.x) >> 6;
    for (int i = wave; i < nnz; i += nwaves) {
        if (!keep_mask(i, nnz)) continue;
        int row = sp_row[i];
        int col = sp_col[i];
        float v = 1.25f * en_emb[(size_t)col * 64 + lane];
        atomicAdd(&hidden[row * 64 + lane], v);
    }
}

__global__ void k_hfinish(float* __restrict__ hidden, const float* __restrict__ user_emb,
                          const int* __restrict__ user_ids, const float* __restrict__ en_off,
                          int B) {
    int t = blockIdx.x * blockDim.x + threadIdx.x;
    if (t >= B * 64) return;
    int b = t >> 6, d = t & 63;
    int uid = user_ids[b];
    float h = hidden[t] + user_emb[(size_t)uid * 64 + d] + en_off[d];
    hidden[t] = tanhf(h);
}

// ===================== fused regularization =================================
__global__ void k_reg(const unsigned char* __restrict__ mask,
                      const float* __restrict__ en_emb, const float* __restrict__ de_emb,
                      const float* __restrict__ de_bias,
                      const float* __restrict__ user_emb, const int* __restrict__ user_ids,
                      const float* __restrict__ en_off,
                      float* __restrict__ reg, int num_items, int B) {
    const int stride = gridDim.x * blockDim.x;
    float s = 0.f;
    for (int t = blockIdx.x * blockDim.x + threadIdx.x; t < num_items * 16; t += stride) {
        int i = t >> 4, l = t & 15;
        if (mask[i]) {
            float4 e = *reinterpret_cast<const float4*>(en_emb + (size_t)i * 64 + l * 4);
            float4 d = *reinterpret_cast<const float4*>(de_emb + (size_t)i * 64 + l * 4);
            s += e.x*e.x + e.y*e.y + e.z*e.z + e.w*e.w
               + d.x*d.x + d.y*d.y + d.z*d.z + d.w*d.w;
            if (l == 0) { float bb = de_bias[i]; s += bb * bb; }
        }
    }
    for (int t = blockIdx.x * blockDim.x + threadIdx.x; t < B * 16; t += stride) {
        int b = t >> 4, l = t & 15;
        int uid = user_ids[b];
        float4 u = *reinterpret_cast<const float4*>(user_emb + (size_t)uid * 64 + l * 4);
        s += u.x*u.x + u.y*u.y + u.z*u.z + u.w*u.w;
    }
    if (blockIdx.x == 0 && threadIdx.x < 64) {
        float o = en_off[threadIdx.x];
        s += o * o;
    }
    for (int m = 1; m < 64; m <<= 1) s += __shfl_xor(s, m);
    __shared__ float wsum[4];
    if ((threadIdx.x & 63) == 0) wsum[threadIdx.x >> 6] = s;
    __syncthreads();
    if (threadIdx.x == 0)
        atomicAdd(reg, 0.5f * (wsum[0] + wsum[1] + wsum[2] + wsum[3]));
}

extern "C" void kernel_launch(void* const* d_in, const int* in_sizes, int n_in,
                              void* d_out, int out_size, void* d_ws, size_t ws_size,
                              hipStream_t stream) {
    const int*   user_ids  = (const int*)  d_in[0];
    const int*   bat_idx   = (const int*)  d_in[1];
    const int*   sp_row    = (const int*)  d_in[2];
    const int*   sp_col    = (const int*)  d_in[3];
    const int*   bat_items = (const int*)  d_in[4];
    const float* en_emb    = (const float*)d_in[5];
    const float* en_off    = (const float*)d_in[6];
    const float* de_emb    = (const float*)d_in[7];
    const float* de_bias   = (const float*)d_in[8];
    const float* user_emb  = (const float*)d_in[9];

    const int B         = in_sizes[0];
    const int N         = in_sizes[1];
    const int NNZ       = in_sizes[2];
    const int NUM_ITEMS = in_sizes[8];

    float* out = (float*)d_out;        // ratings [N]
    float* reg = out + N;              // reg_loss scalar

    // workspace: [mask | cursor | rowcur] one small memset; rest no-init.
    char* ws = (char*)d_ws;
    size_t off = 0;
    unsigned char* mask = (unsigned char*)(ws + off);
    off += ((size_t)NUM_ITEMS + 255) & ~(size_t)255;
    int* cursor = (int*)(ws + off);               off += 256;
    int* rowcur = (int*)(ws + off);               off += (size_t)B * 4;
    const size_t zero_bytes = off;
    float* hidden = (float*)(ws + off);           off += (size_t)B * 64 * 4;  // fallback only
    unsigned* perm   = (unsigned*)(ws + off);     off += (size_t)NB * CAPB * 4;
    unsigned* inv    = (unsigned*)(ws + off);     off += (size_t)N * 4;
    float*    r_perm = (float*)(ws + off);
    unsigned* srow   = (unsigned*)r_perm;         // alias: disjoint lifetimes
    size_t tail = (size_t)NB * CAPB * 4;
    if ((size_t)B * CAPR * 4 > tail) tail = (size_t)B * CAPR * 4;
    off += tail;
    unsigned short* hb   = (unsigned short*)(ws + off);  off += (size_t)B * 64 * 2;
    off = (off + 7) & ~(size_t)7;
    unsigned short* debf = (unsigned short*)(ws + off);  off += (size_t)NUM_ITEMS * 64 * 2;

    const bool sorted_path =
        (ws_size >= off) && (N == (1 << 20)) && (B == 4096) &&
        (NUM_ITEMS <= (1 << 17)) && (NUM_ITEMS >= 65536) &&
        (NUM_ITEMS % 4 == 0) &&
        (NNZ % (RSB * 256) == 0) && (NNZ / RSB <= CAPR * 256);

    hipMemsetAsync(ws, 0, zero_bytes, stream);
    hipMemsetAsync(reg, 0, sizeof(float), stream);

    if (sorted_path) {
        k_bucket <<<256 + CVTB, 256, 0, stream>>>(bat_idx, bat_items, mask, cursor, perm, inv,
                                                  de_emb, debf, N, NUM_ITEMS);
        k_rowsort<<<RSB, 256, 0, stream>>>(sp_row, sp_col, rowcur, srow, NNZ, B);
        k_hidden <<<(B * 64 + 255) / 256, 256, 0, stream>>>(
            srow, rowcur, en_emb, user_emb, user_ids, en_off, hb, B);
        k_ratings_bkt<<<FATB, 256, 0, stream>>>(hb, debf, de_bias, perm, cursor, r_perm);
        k_unperm<<<1024, 256, 0, stream>>>(inv, r_perm, out, N);
    } else {
        hipMemsetAsync(hidden, 0, (size_t)B * 64 * 4, stream);
        k_mask<<<(N + 255) / 256, 256, 0, stream>>>(bat_items, mask, N);
        k_scatter<<<FATB, 256, 0, stream>>>(sp_row, sp_col, en_emb, hidden, NNZ);
        k_hfinish<<<(B * 64 + 255) / 256, 256, 0, stream>>>(hidden, user_emb, user_ids,
                                                            en_off, B);
        k_ratings<<<FATB, 256, 0, stream>>>(hidden, de_emb, de_bias, bat_idx, bat_items, out, N);
    }

    k_reg<<<256, 256, 0, stream>>>(mask, en_emb, de_emb, de_bias,
                                   user_emb, user_ids, en_off, reg, NUM_ITEMS, B);
}

// Round 9
// 202.681 us; speedup vs baseline: 1.4096x; 1.1591x over previous
//
#include <hip/hip_runtime.h>
#include <hip/hip_bf16.h>

// ---------------------------------------------------------------------------
// CDAE forward. Round 9: phase fusion; bf16 ratings kept.
// R8 post-mortem: top-5 = harness 0xAA ws-poison fills (3 x 40us, 256MiB
// WRITE each) -- ~120us immovable. Our kernels all <40us. ratings bf16 win
// (40.8 -> ~23) was eaten by +cvt and dispatch serialization (total -1.6us).
// R9: (1) fuse independent phases by block range: D1 bucket||rowsort||cvt,
// D2 hidden||reg (reg's 77MB stream overlaps latency-bound hidden gathers,
// warms L3 with en_emb), D3 ratings, D4 unperm+reg-final. 6 kernels+2 memsets
// -> 4 kernels+1 memset. (2) ratings 4 independent gather chains.
// If delta < ~5us: harness floor reached (fills+restores ~135us + our
// memory-bound ~85us) -> ROOFLINE.
// ---------------------------------------------------------------------------
#define PARTITIONABLE 1
#define NB 8               // item-slice buckets == XCDs (blockIdx&7 pinning)
#define CAPB 136192        // per-item-bucket capacity; E=131072, +14 sigma
#define FATB 2048          // fat grid size for ratings
#define CAPR 128           // per-row capacity; E=50
#define RSB 200            // rowsort blocks: NNZ=204800 = 200 * 4 * 256
#define CVTB 512           // de_emb fp32->bf16 cvt blocks
#define HBLK 1024          // hidden blocks (B*64/256)
#define REGB 256           // reg partial blocks

__device__ __forceinline__ unsigned rotl32(unsigned x, int r) {
    return (x << r) | (x >> (32 - r));
}

__device__ __forceinline__ void threefry2x32(unsigned k0, unsigned k1,
                                             unsigned& x0, unsigned& x1) {
    unsigned ks0 = k0, ks1 = k1, ks2 = k0 ^ k1 ^ 0x1BD11BDAu;
    x0 += ks0; x1 += ks1;
#define TF_R(r) { x0 += x1; x1 = rotl32(x1, r); x1 ^= x0; }
    TF_R(13) TF_R(15) TF_R(26) TF_R(6)   x0 += ks1; x1 += ks2 + 1u;
    TF_R(17) TF_R(29) TF_R(16) TF_R(24)  x0 += ks2; x1 += ks0 + 2u;
    TF_R(13) TF_R(15) TF_R(26) TF_R(6)   x0 += ks0; x1 += ks1 + 3u;
    TF_R(17) TF_R(29) TF_R(16) TF_R(24)  x0 += ks1; x1 += ks2 + 4u;
    TF_R(13) TF_R(15) TF_R(26) TF_R(6)   x0 += ks2; x1 += ks0 + 5u;
#undef TF_R
}

__device__ __forceinline__ bool keep_mask(int i, int nnz) {
#if PARTITIONABLE
    unsigned x0 = 0u, x1 = (unsigned)i;
    threefry2x32(0u, 42u, x0, x1);
    unsigned bits = x0 ^ x1;
#else
    int half = nnz >> 1;
    int j = (i < half) ? i : i - half;
    unsigned x0 = (unsigned)j, x1 = (unsigned)(j + half);
    threefry2x32(0u, 42u, x0, x1);
    unsigned bits = (i < half) ? x0 : x1;
#endif
    float u = __uint_as_float((bits >> 9) | 0x3f800000u) - 1.0f;
    return u < 0.8f;
}

// fp32 -> bf16 round-to-nearest-even
__device__ __forceinline__ unsigned short f2bf(float f) {
    unsigned u = __float_as_uint(f);
    return (unsigned short)((u + 0x7FFFu + ((u >> 16) & 1u)) >> 16);
}

// dot of 4 bf16 pairs packed in uint2, fp32 accumulate
__device__ __forceinline__ float bfdot4(uint2 h, uint2 d) {
    float s;
    s  = __uint_as_float(h.x << 16)         * __uint_as_float(d.x << 16);
    s += __uint_as_float(h.x & 0xFFFF0000u) * __uint_as_float(d.x & 0xFFFF0000u);
    s += __uint_as_float(h.y << 16)         * __uint_as_float(d.y << 16);
    s += __uint_as_float(h.y & 0xFFFF0000u) * __uint_as_float(d.y & 0xFFFF0000u);
    return s;
}

// ============ D1: bucket (0..255) || rowsort (256..455) || cvt (456..967) ===
__global__ void k_prep(const int* __restrict__ bat_idx, const int* __restrict__ bat_items,
                       unsigned char* __restrict__ mask, int* __restrict__ cursor,
                       unsigned* __restrict__ perm, unsigned* __restrict__ inv,
                       const int* __restrict__ sp_row, const int* __restrict__ sp_col,
                       int* __restrict__ rowcur, unsigned* __restrict__ srow,
                       const float* __restrict__ de_emb, unsigned short* __restrict__ debf,
                       int N, int num_items, int nnz, int B) {
    __shared__ int sh[4096];                       // 16KB, shared by both branches
    if (blockIdx.x < 256) {
        // ---- pair bucketing by item slice ----
        if (threadIdx.x < NB) sh[threadIdx.x] = 0;
        __syncthreads();
        const int per = N / 256;                   // 4096
        const int base_n = blockIdx.x * per;
        const int iters = per / blockDim.x;        // 16
        unsigned packed[16];
        int bkt[16];
        for (int it = 0; it < iters; ++it) {
            int n = base_n + it * blockDim.x + threadIdx.x;
            int item = bat_items[n];
            int bidx = bat_idx[n];
            mask[item] = 1;
            int b = (int)(((unsigned long long)(unsigned)item * NB) / (unsigned)num_items);
            packed[it] = ((unsigned)item << 12) | (unsigned)bidx;   // item:17|bidx:12
            bkt[it] = b;
            atomicAdd(&sh[b], 1);
        }
        __syncthreads();
        if (threadIdx.x < NB) {
            int c = sh[threadIdx.x];
            sh[threadIdx.x] = atomicAdd(&cursor[threadIdx.x], c);
        }
        __syncthreads();
        for (int it = 0; it < iters; ++it) {
            int n = base_n + it * blockDim.x + threadIdx.x;
            int pos = atomicAdd(&sh[bkt[it]], 1);
            unsigned gpos = (unsigned)bkt[it] * CAPB + (unsigned)min(pos, CAPB - 1);
            perm[gpos] = packed[it];   // contiguous per-(block,bucket) runs
            inv[n] = gpos;             // coalesced
        }
    } else if (blockIdx.x < 256 + RSB) {
        // ---- nnz counting-sort by row; payload col<<1|keep ----
        const int blk = blockIdx.x - 256;
        for (int i = threadIdx.x; i < B; i += blockDim.x) sh[i] = 0;
        __syncthreads();
        const int per = nnz / RSB;                 // 1024
        const int base = blk * per;
        const int iters = per / blockDim.x;        // 4
        unsigned pk[8];
        int rw[8];
        for (int it = 0; it < iters; ++it) {
            int i = base + it * blockDim.x + threadIdx.x;
            int row = sp_row[i];
            int col = sp_col[i];
            unsigned k = keep_mask(i, nnz) ? 1u : 0u;
            pk[it] = ((unsigned)col << 1) | k;
            rw[it] = row;
            atomicAdd(&sh[row], 1);
        }
        __syncthreads();
        for (int i = threadIdx.x; i < B; i += blockDim.x) {
            int c = sh[i];
            if (c) sh[i] = atomicAdd(&rowcur[i], c);
        }
        __syncthreads();
        for (int it = 0; it < iters; ++it) {
            int pos = atomicAdd(&sh[rw[it]], 1);
            srow[(size_t)rw[it] * CAPR + min(pos, CAPR - 1)] = pk[it];
        }
    } else {
        // ---- de_emb fp32 -> bf16, coalesced stream ----
        const int quads = num_items * 16;
        const int stride = CVTB * blockDim.x;
        for (int q = (int)(blockIdx.x - 256 - RSB) * blockDim.x + threadIdx.x; q < quads;
             q += stride) {
            float4 v = reinterpret_cast<const float4*>(de_emb)[q];
            ushort4 o;
            o.x = f2bf(v.x); o.y = f2bf(v.y); o.z = f2bf(v.z); o.w = f2bf(v.w);
            reinterpret_cast<ushort4*>(debf)[q] = o;
        }
    }
}

// ============ D2: hidden (0..1023) || reg partials (1024..1279) =============
__global__ void k_hidden_reg(const unsigned* __restrict__ srow, const int* __restrict__ rowcur,
                             const float* __restrict__ en_emb, const float* __restrict__ user_emb,
                             const int* __restrict__ user_ids, const float* __restrict__ en_off,
                             unsigned short* __restrict__ hb,
                             const unsigned char* __restrict__ mask,
                             const float* __restrict__ de_emb, const float* __restrict__ de_bias,
                             float* __restrict__ reg_ws, int B, int num_items) {
    if (blockIdx.x < HBLK) {
        // ---- hidden: one wave per row, register accumulate, bf16 store ----
        const int lane = threadIdx.x & 63;
        const int row = (blockIdx.x * blockDim.x + threadIdx.x) >> 6;
        if (row >= B) return;
        const int cnt = min(rowcur[row], CAPR);
        const unsigned* sr = srow + (size_t)row * CAPR;
        float acc0 = 0.f, acc1 = 0.f;
        for (int j0 = 0; j0 < cnt; j0 += 64) {
            unsigned ev = (j0 + lane < cnt) ? sr[j0 + lane] : 0u;
            int m = min(64, cnt - j0);
            int jj = 0;
            for (; jj + 1 < m; jj += 2) {
                unsigned e0 = __shfl(ev, jj);
                unsigned e1 = __shfl(ev, jj + 1);
                if (e0 & 1u) acc0 += en_emb[(size_t)(e0 >> 1) * 64 + lane];
                if (e1 & 1u) acc1 += en_emb[(size_t)(e1 >> 1) * 64 + lane];
            }
            if (jj < m) {
                unsigned e0 = __shfl(ev, jj);
                if (e0 & 1u) acc0 += en_emb[(size_t)(e0 >> 1) * 64 + lane];
            }
        }
        int uid = user_ids[row];
        float hval = 1.25f * (acc0 + acc1) + user_emb[(size_t)uid * 64 + lane] + en_off[lane];
        hb[(size_t)row * 64 + lane] = f2bf(tanhf(hval));
    } else {
        // ---- reg partial sums (atomic into zeroed reg_ws) ----
        const int bx = blockIdx.x - HBLK;
        const int stride = REGB * blockDim.x;
        float s = 0.f;
        for (int t = bx * blockDim.x + threadIdx.x; t < num_items * 16; t += stride) {
            int i = t >> 4, l = t & 15;
            if (mask[i]) {
                float4 e = *reinterpret_cast<const float4*>(en_emb + (size_t)i * 64 + l * 4);
                float4 d = *reinterpret_cast<const float4*>(de_emb + (size_t)i * 64 + l * 4);
                s += e.x*e.x + e.y*e.y + e.z*e.z + e.w*e.w
                   + d.x*d.x + d.y*d.y + d.z*d.z + d.w*d.w;
                if (l == 0) { float bb = de_bias[i]; s += bb * bb; }
            }
        }
        for (int t = bx * blockDim.x + threadIdx.x; t < B * 16; t += stride) {
            int b = t >> 4, l = t & 15;
            int uid = user_ids[b];
            float4 u = *reinterpret_cast<const float4*>(user_emb + (size_t)uid * 64 + l * 4);
            s += u.x*u.x + u.y*u.y + u.z*u.z + u.w*u.w;
        }
        if (bx == 0 && threadIdx.x < 64) {
            float o = en_off[threadIdx.x];
            s += o * o;
        }
        for (int m = 1; m < 64; m <<= 1) s += __shfl_xor(s, m);
        __shared__ float wsum[4];
        if ((threadIdx.x & 63) == 0) wsum[threadIdx.x >> 6] = s;
        __syncthreads();
        if (threadIdx.x == 0)
            atomicAdd(reg_ws, wsum[0] + wsum[1] + wsum[2] + wsum[3]);
    }
}

// ============ D3: ratings, bf16 gathers, 4 chains, XCD-pinned buckets =======
__global__ void k_ratings_bkt(const unsigned short* __restrict__ hb,
                              const unsigned short* __restrict__ debf,
                              const float* __restrict__ de_bias,
                              const unsigned* __restrict__ perm, const int* __restrict__ cursor,
                              float* __restrict__ r_perm) {
    const int bkt = blockIdx.x & (NB - 1);
    const int cnt = cursor[bkt];
    const int l = threadIdx.x & 15;
    const int gid = (blockIdx.x >> 3) * (blockDim.x >> 4) + (threadIdx.x >> 4);
    const int gpb = (gridDim.x >> 3) * (blockDim.x >> 4);
    const unsigned* pb = perm + (size_t)bkt * CAPB;
    float* rb = r_perm + (size_t)bkt * CAPB;

    int slot = gid;
    for (; slot + 3 * gpb < cnt; slot += 4 * gpb) {        // 4 independent chains
        unsigned p0 = pb[slot];
        unsigned p1 = pb[slot + gpb];
        unsigned p2 = pb[slot + 2 * gpb];
        unsigned p3 = pb[slot + 3 * gpb];
        int it0 = (int)(p0 >> 12), b0 = (int)(p0 & 0xFFFu);
        int it1 = (int)(p1 >> 12), b1 = (int)(p1 & 0xFFFu);
        int it2 = (int)(p2 >> 12), b2 = (int)(p2 & 0xFFFu);
        int it3 = (int)(p3 >> 12), b3 = (int)(p3 & 0xFFFu);
        uint2 h0 = *reinterpret_cast<const uint2*>(hb   + (size_t)b0  * 64 + l * 4);
        uint2 d0 = *reinterpret_cast<const uint2*>(debf + (size_t)it0 * 64 + l * 4);
        uint2 h1 = *reinterpret_cast<const uint2*>(hb   + (size_t)b1  * 64 + l * 4);
        uint2 d1 = *reinterpret_cast<const uint2*>(debf + (size_t)it1 * 64 + l * 4);
        uint2 h2 = *reinterpret_cast<const uint2*>(hb   + (size_t)b2  * 64 + l * 4);
        uint2 d2 = *reinterpret_cast<const uint2*>(debf + (size_t)it2 * 64 + l * 4);
        uint2 h3 = *reinterpret_cast<const uint2*>(hb   + (size_t)b3  * 64 + l * 4);
        uint2 d3 = *reinterpret_cast<const uint2*>(debf + (size_t)it3 * 64 + l * 4);
        float s0 = bfdot4(h0, d0);
        float s1 = bfdot4(h1, d1);
        float s2 = bfdot4(h2, d2);
        float s3 = bfdot4(h3, d3);
        s0 += __shfl_xor(s0, 1); s1 += __shfl_xor(s1, 1);
        s2 += __shfl_xor(s2, 1); s3 += __shfl_xor(s3, 1);
        s0 += __shfl_xor(s0, 2); s1 += __shfl_xor(s1, 2);
        s2 += __shfl_xor(s2, 2); s3 += __shfl_xor(s3, 2);
        s0 += __shfl_xor(s0, 4); s1 += __shfl_xor(s1, 4);
        s2 += __shfl_xor(s2, 4); s3 += __shfl_xor(s3, 4);
        s0 += __shfl_xor(s0, 8); s1 += __shfl_xor(s1, 8);
        s2 += __shfl_xor(s2, 8); s3 += __shfl_xor(s3, 8);
        if (l == 0) {
            rb[slot]           = s0 + de_bias[it0];
            rb[slot + gpb]     = s1 + de_bias[it1];
            rb[slot + 2 * gpb] = s2 + de_bias[it2];
            rb[slot + 3 * gpb] = s3 + de_bias[it3];
        }
    }
    for (; slot < cnt; slot += gpb) {
        unsigned p = pb[slot];
        int item = (int)(p >> 12), bidx = (int)(p & 0xFFFu);
        uint2 hv = *reinterpret_cast<const uint2*>(hb   + (size_t)bidx * 64 + l * 4);
        uint2 dv = *reinterpret_cast<const uint2*>(debf + (size_t)item * 64 + l * 4);
        float s = bfdot4(hv, dv);
        s += __shfl_xor(s, 1);
        s += __shfl_xor(s, 2);
        s += __shfl_xor(s, 4);
        s += __shfl_xor(s, 8);
        if (l == 0) rb[slot] = s + de_bias[item];
    }
}

// ============ D4: unpermute + reg finalize ==================================
__global__ void k_unperm(const unsigned* __restrict__ inv, const float* __restrict__ r_perm,
                         const float* __restrict__ reg_ws, float* __restrict__ out, int N) {
    const int stride = gridDim.x * blockDim.x;
    for (int t = blockIdx.x * blockDim.x + threadIdx.x; t < N; t += stride)
        out[t] = r_perm[inv[t]];
    if (blockIdx.x == 0 && threadIdx.x == 0)
        out[N] = 0.5f * reg_ws[0];
}

// ===================== fallback (direct) path ===============================
__global__ void k_mask(const int* __restrict__ bat_items, unsigned char* __restrict__ mask,
                       int N) {
    int t = blockIdx.x * blockDim.x + threadIdx.x;
    if (t < N) mask[bat_items[t]] = 1;
}

__global__ void k_ratings(const float* __restrict__ hidden, const float* __restrict__ de_emb,
                          const float* __restrict__ de_bias,
                          const int* __restrict__ bat_idx, const int* __restrict__ bat_items,
                          float* __restrict__ out, int N) {
    const int l = threadIdx.x & 15;
    const int gid = (blockIdx.x * blockDim.x + threadIdx.x) >> 4;
    const int gstride = (gridDim.x * blockDim.x) >> 4;
    for (int n = gid; n < N; n += gstride) {
        int b  = bat_idx[n];
        int it = bat_items[n];
        float4 hv = *reinterpret_cast<const float4*>(hidden + (size_t)b  * 64 + l * 4);
        float4 dv = *reinterpret_cast<const float4*>(de_emb + (size_t)it * 64 + l * 4);
        float s = hv.x*dv.x + hv.y*dv.y + hv.z*dv.z + hv.w*dv.w;
        s += __shfl_xor(s, 1);
        s += __shfl_xor(s, 2);
        s += __shfl_xor(s, 4);
        s += __shfl_xor(s, 8);
        if (l == 0) out[n] = s + de_bias[it];
    }
}

__global__ void k_scatter(const int* __restrict__ sp_row, const int* __restrict__ sp_col,
                          const float* __restrict__ en_emb, float* __restrict__ hidden,
                          int nnz) {
    const int lane = threadIdx.x & 63;
    const int wave = (blockIdx.x * blockDim.x + threadIdx.x) >> 6;
    const int nwaves = (gridDim.x * blockDim.x) >> 6;
    for (int i = wave; i < nnz; i += nwaves) {
        if (!keep_mask(i, nnz)) continue;
        int row = sp_row[i];
        int col = sp_col[i];
        float v = 1.25f * en_emb[(size_t)col * 64 + lane];
        atomicAdd(&hidden[row * 64 + lane], v);
    }
}

__global__ void k_hfinish(float* __restrict__ hidden, const float* __restrict__ user_emb,
                          const int* __restrict__ user_ids, const float* __restrict__ en_off,
                          int B) {
    int t = blockIdx.x * blockDim.x + threadIdx.x;
    if (t >= B * 64) return;
    int b = t >> 6, d = t & 63;
    int uid = user_ids[b];
    float h = hidden[t] + user_emb[(size_t)uid * 64 + d] + en_off[d];
    hidden[t] = tanhf(h);
}

__global__ void k_reg_fb(const unsigned char* __restrict__ mask,
                         const float* __restrict__ en_emb, const float* __restrict__ de_emb,
                         const float* __restrict__ de_bias,
                         const float* __restrict__ user_emb, const int* __restrict__ user_ids,
                         const float* __restrict__ en_off,
                         float* __restrict__ reg, int num_items, int B) {
    const int stride = gridDim.x * blockDim.x;
    float s = 0.f;
    for (int t = blockIdx.x * blockDim.x + threadIdx.x; t < num_items * 16; t += stride) {
        int i = t >> 4, l = t & 15;
        if (mask[i]) {
            float4 e = *reinterpret_cast<const float4*>(en_emb + (size_t)i * 64 + l * 4);
            float4 d = *reinterpret_cast<const float4*>(de_emb + (size_t)i * 64 + l * 4);
            s += e.x*e.x + e.y*e.y + e.z*e.z + e.w*e.w
               + d.x*d.x + d.y*d.y + d.z*d.z + d.w*d.w;
            if (l == 0) { float bb = de_bias[i]; s += bb * bb; }
        }
    }
    for (int t = blockIdx.x * blockDim.x + threadIdx.x; t < B * 16; t += stride) {
        int b = t >> 4, l = t & 15;
        int uid = user_ids[b];
        float4 u = *reinterpret_cast<const float4*>(user_emb + (size_t)uid * 64 + l * 4);
        s += u.x*u.x + u.y*u.y + u.z*u.z + u.w*u.w;
    }
    if (blockIdx.x == 0 && threadIdx.x < 64) {
        float o = en_off[threadIdx.x];
        s += o * o;
    }
    for (int m = 1; m < 64; m <<= 1) s += __shfl_xor(s, m);
    __shared__ float wsum[4];
    if ((threadIdx.x & 63) == 0) wsum[threadIdx.x >> 6] = s;
    __syncthreads();
    if (threadIdx.x == 0)
        atomicAdd(reg, 0.5f * (wsum[0] + wsum[1] + wsum[2] + wsum[3]));
}

extern "C" void kernel_launch(void* const* d_in, const int* in_sizes, int n_in,
                              void* d_out, int out_size, void* d_ws, size_t ws_size,
                              hipStream_t stream) {
    const int*   user_ids  = (const int*)  d_in[0];
    const int*   bat_idx   = (const int*)  d_in[1];
    const int*   sp_row    = (const int*)  d_in[2];
    const int*   sp_col    = (const int*)  d_in[3];
    const int*   bat_items = (const int*)  d_in[4];
    const float* en_emb    = (const float*)d_in[5];
    const float* en_off    = (const float*)d_in[6];
    const float* de_emb    = (const float*)d_in[7];
    const float* de_bias   = (const float*)d_in[8];
    const float* user_emb  = (const float*)d_in[9];

    const int B         = in_sizes[0];
    const int N         = in_sizes[1];
    const int NNZ       = in_sizes[2];
    const int NUM_ITEMS = in_sizes[8];

    float* out = (float*)d_out;        // ratings [N]; reg scalar at out[N]

    // workspace: [mask | cursor | rowcur | reg_ws] one memset; rest no-init.
    char* ws = (char*)d_ws;
    size_t off = 0;
    unsigned char* mask = (unsigned char*)(ws + off);
    off += ((size_t)NUM_ITEMS + 255) & ~(size_t)255;
    int* cursor = (int*)(ws + off);               off += 256;
    int* rowcur = (int*)(ws + off);               off += (size_t)B * 4;
    float* reg_ws = (float*)(ws + off);           off += 256;
    const size_t zero_bytes = off;
    float* hidden = (float*)(ws + off);           off += (size_t)B * 64 * 4;  // fallback only
    unsigned* perm   = (unsigned*)(ws + off);     off += (size_t)NB * CAPB * 4;
    unsigned* inv    = (unsigned*)(ws + off);     off += (size_t)N * 4;
    float*    r_perm = (float*)(ws + off);
    unsigned* srow   = (unsigned*)r_perm;         // alias: disjoint lifetimes
    size_t tail = (size_t)NB * CAPB * 4;
    if ((size_t)B * CAPR * 4 > tail) tail = (size_t)B * CAPR * 4;
    off += tail;
    unsigned short* hb   = (unsigned short*)(ws + off);  off += (size_t)B * 64 * 2;
    off = (off + 7) & ~(size_t)7;
    unsigned short* debf = (unsigned short*)(ws + off);  off += (size_t)NUM_ITEMS * 64 * 2;

    const bool sorted_path =
        (ws_size >= off) && (N == (1 << 20)) && (B == 4096) &&
        (NUM_ITEMS <= (1 << 17)) && (NUM_ITEMS >= 65536) &&
        (NUM_ITEMS % 4 == 0) &&
        (NNZ % (RSB * 256) == 0) && (NNZ / RSB <= CAPR * 256);

    hipMemsetAsync(ws, 0, zero_bytes, stream);

    if (sorted_path) {
        k_prep<<<256 + RSB + CVTB, 256, 0, stream>>>(
            bat_idx, bat_items, mask, cursor, perm, inv,
            sp_row, sp_col, rowcur, srow, de_emb, debf, N, NUM_ITEMS, NNZ, B);
        k_hidden_reg<<<HBLK + REGB, 256, 0, stream>>>(
            srow, rowcur, en_emb, user_emb, user_ids, en_off, hb,
            mask, de_emb, de_bias, reg_ws, B, NUM_ITEMS);
        k_ratings_bkt<<<FATB, 256, 0, stream>>>(hb, debf, de_bias, perm, cursor, r_perm);
        k_unperm<<<1024, 256, 0, stream>>>(inv, r_perm, reg_ws, out, N);
    } else {
        hipMemsetAsync(hidden, 0, (size_t)B * 64 * 4, stream);
        hipMemsetAsync(out + N, 0, sizeof(float), stream);
        k_mask<<<(N + 255) / 256, 256, 0, stream>>>(bat_items, mask, N);
        k_scatter<<<FATB, 256, 0, stream>>>(sp_row, sp_col, en_emb, hidden, NNZ);
        k_hfinish<<<(B * 64 + 255) / 256, 256, 0, stream>>>(hidden, user_emb, user_ids,
                                                            en_off, B);
        k_ratings<<<FATB, 256, 0, stream>>>(hidden, de_emb, de_bias, bat_idx, bat_items, out, N);
        k_reg_fb<<<REGB, 256, 0, stream>>>(mask, en_emb, de_emb, de_bias,
                                           user_emb, user_ids, en_off, out + N, NUM_ITEMS, B);
    }
}

// Round 10
// 196.126 us; speedup vs baseline: 1.4567x; 1.0334x over previous
//
#include <hip/hip_runtime.h>
#include <hip/hip_bf16.h>

// ---------------------------------------------------------------------------
// CDAE forward. Round 10: ratings 8-lane groups (uint4), vectorized unperm.
// R9 post-mortem: 235->202.7us. Top-5 all harness 0xAA ws-poison fills
// (3 x 41us x 256MiB WRITE = ~124us immovable); ours ~79us. Phase-fusion
// overlap theory held (D2 hidden||reg -> max not sum).
// R10: ratings is issue/latency-bound (23us vs ~6.5us line floor). 8-lane
// groups w/ uint4 loads: one wave-load serves 8 pairs (was 4), reduce 4->3
// shfl stages => ~2x fewer inst/pair, line traffic unchanged. unperm: uint4
// inv + float4 out stores. Predict total ~195us; if gain <3us => ROOFLINE
// (harness fills + latency-floor gathers).
// ---------------------------------------------------------------------------
#define PARTITIONABLE 1
#define NB 8               // item-slice buckets == XCDs (blockIdx&7 pinning)
#define CAPB 136192        // per-item-bucket capacity; E=131072, +14 sigma
#define FATB 2048          // fat grid size for ratings
#define CAPR 128           // per-row capacity; E=50
#define RSB 200            // rowsort blocks: NNZ=204800 = 200 * 4 * 256
#define CVTB 512           // de_emb fp32->bf16 cvt blocks
#define HBLK 1024          // hidden blocks (B*64/256)
#define REGB 256           // reg partial blocks

__device__ __forceinline__ unsigned rotl32(unsigned x, int r) {
    return (x << r) | (x >> (32 - r));
}

__device__ __forceinline__ void threefry2x32(unsigned k0, unsigned k1,
                                             unsigned& x0, unsigned& x1) {
    unsigned ks0 = k0, ks1 = k1, ks2 = k0 ^ k1 ^ 0x1BD11BDAu;
    x0 += ks0; x1 += ks1;
#define TF_R(r) { x0 += x1; x1 = rotl32(x1, r); x1 ^= x0; }
    TF_R(13) TF_R(15) TF_R(26) TF_R(6)   x0 += ks1; x1 += ks2 + 1u;
    TF_R(17) TF_R(29) TF_R(16) TF_R(24)  x0 += ks2; x1 += ks0 + 2u;
    TF_R(13) TF_R(15) TF_R(26) TF_R(6)   x0 += ks0; x1 += ks1 + 3u;
    TF_R(17) TF_R(29) TF_R(16) TF_R(24)  x0 += ks1; x1 += ks2 + 4u;
    TF_R(13) TF_R(15) TF_R(26) TF_R(6)   x0 += ks2; x1 += ks0 + 5u;
#undef TF_R
}

__device__ __forceinline__ bool keep_mask(int i, int nnz) {
#if PARTITIONABLE
    unsigned x0 = 0u, x1 = (unsigned)i;
    threefry2x32(0u, 42u, x0, x1);
    unsigned bits = x0 ^ x1;
#else
    int half = nnz >> 1;
    int j = (i < half) ? i : i - half;
    unsigned x0 = (unsigned)j, x1 = (unsigned)(j + half);
    threefry2x32(0u, 42u, x0, x1);
    unsigned bits = (i < half) ? x0 : x1;
#endif
    float u = __uint_as_float((bits >> 9) | 0x3f800000u) - 1.0f;
    return u < 0.8f;
}

// fp32 -> bf16 round-to-nearest-even
__device__ __forceinline__ unsigned short f2bf(float f) {
    unsigned u = __float_as_uint(f);
    return (unsigned short)((u + 0x7FFFu + ((u >> 16) & 1u)) >> 16);
}

// dot of 8 bf16 pairs packed in uint4, fp32 accumulate
__device__ __forceinline__ float bfdot8(uint4 h, uint4 d) {
    float s;
    s  = __uint_as_float(h.x << 16)         * __uint_as_float(d.x << 16);
    s += __uint_as_float(h.x & 0xFFFF0000u) * __uint_as_float(d.x & 0xFFFF0000u);
    s += __uint_as_float(h.y << 16)         * __uint_as_float(d.y << 16);
    s += __uint_as_float(h.y & 0xFFFF0000u) * __uint_as_float(d.y & 0xFFFF0000u);
    s += __uint_as_float(h.z << 16)         * __uint_as_float(d.z << 16);
    s += __uint_as_float(h.z & 0xFFFF0000u) * __uint_as_float(d.z & 0xFFFF0000u);
    s += __uint_as_float(h.w << 16)         * __uint_as_float(d.w << 16);
    s += __uint_as_float(h.w & 0xFFFF0000u) * __uint_as_float(d.w & 0xFFFF0000u);
    return s;
}

// ============ D1: bucket (0..255) || rowsort (256..455) || cvt (456..967) ===
__global__ void k_prep(const int* __restrict__ bat_idx, const int* __restrict__ bat_items,
                       unsigned char* __restrict__ mask, int* __restrict__ cursor,
                       unsigned* __restrict__ perm, unsigned* __restrict__ inv,
                       const int* __restrict__ sp_row, const int* __restrict__ sp_col,
                       int* __restrict__ rowcur, unsigned* __restrict__ srow,
                       const float* __restrict__ de_emb, unsigned short* __restrict__ debf,
                       int N, int num_items, int nnz, int B) {
    __shared__ int sh[4096];                       // 16KB, shared by both branches
    if (blockIdx.x < 256) {
        // ---- pair bucketing by item slice ----
        if (threadIdx.x < NB) sh[threadIdx.x] = 0;
        __syncthreads();
        const int per = N / 256;                   // 4096
        const int base_n = blockIdx.x * per;
        const int iters = per / blockDim.x;        // 16
        unsigned packed[16];
        int bkt[16];
        for (int it = 0; it < iters; ++it) {
            int n = base_n + it * blockDim.x + threadIdx.x;
            int item = bat_items[n];
            int bidx = bat_idx[n];
            mask[item] = 1;
            int b = (int)(((unsigned long long)(unsigned)item * NB) / (unsigned)num_items);
            packed[it] = ((unsigned)item << 12) | (unsigned)bidx;   // item:17|bidx:12
            bkt[it] = b;
            atomicAdd(&sh[b], 1);
        }
        __syncthreads();
        if (threadIdx.x < NB) {
            int c = sh[threadIdx.x];
            sh[threadIdx.x] = atomicAdd(&cursor[threadIdx.x], c);
        }
        __syncthreads();
        for (int it = 0; it < iters; ++it) {
            int n = base_n + it * blockDim.x + threadIdx.x;
            int pos = atomicAdd(&sh[bkt[it]], 1);
            unsigned gpos = (unsigned)bkt[it] * CAPB + (unsigned)min(pos, CAPB - 1);
            perm[gpos] = packed[it];   // contiguous per-(block,bucket) runs
            inv[n] = gpos;             // coalesced
        }
    } else if (blockIdx.x < 256 + RSB) {
        // ---- nnz counting-sort by row; payload col<<1|keep ----
        const int blk = blockIdx.x - 256;
        for (int i = threadIdx.x; i < B; i += blockDim.x) sh[i] = 0;
        __syncthreads();
        const int per = nnz / RSB;                 // 1024
        const int base = blk * per;
        const int iters = per / blockDim.x;        // 4
        unsigned pk[8];
        int rw[8];
        for (int it = 0; it < iters; ++it) {
            int i = base + it * blockDim.x + threadIdx.x;
            int row = sp_row[i];
            int col = sp_col[i];
            unsigned k = keep_mask(i, nnz) ? 1u : 0u;
            pk[it] = ((unsigned)col << 1) | k;
            rw[it] = row;
            atomicAdd(&sh[row], 1);
        }
        __syncthreads();
        for (int i = threadIdx.x; i < B; i += blockDim.x) {
            int c = sh[i];
            if (c) sh[i] = atomicAdd(&rowcur[i], c);
        }
        __syncthreads();
        for (int it = 0; it < iters; ++it) {
            int pos = atomicAdd(&sh[rw[it]], 1);
            srow[(size_t)rw[it] * CAPR + min(pos, CAPR - 1)] = pk[it];
        }
    } else {
        // ---- de_emb fp32 -> bf16, coalesced stream ----
        const int quads = num_items * 16;
        const int stride = CVTB * blockDim.x;
        for (int q = (int)(blockIdx.x - 256 - RSB) * blockDim.x + threadIdx.x; q < quads;
             q += stride) {
            float4 v = reinterpret_cast<const float4*>(de_emb)[q];
            ushort4 o;
            o.x = f2bf(v.x); o.y = f2bf(v.y); o.z = f2bf(v.z); o.w = f2bf(v.w);
            reinterpret_cast<ushort4*>(debf)[q] = o;
        }
    }
}

// ============ D2: hidden (0..1023) || reg partials (1024..1279) =============
__global__ void k_hidden_reg(const unsigned* __restrict__ srow, const int* __restrict__ rowcur,
                             const float* __restrict__ en_emb, const float* __restrict__ user_emb,
                             const int* __restrict__ user_ids, const float* __restrict__ en_off,
                             unsigned short* __restrict__ hb,
                             const unsigned char* __restrict__ mask,
                             const float* __restrict__ de_emb, const float* __restrict__ de_bias,
                             float* __restrict__ reg_ws, int B, int num_items) {
    if (blockIdx.x < HBLK) {
        // ---- hidden: one wave per row, register accumulate, bf16 store ----
        const int lane = threadIdx.x & 63;
        const int row = (blockIdx.x * blockDim.x + threadIdx.x) >> 6;
        if (row >= B) return;
        const int cnt = min(rowcur[row], CAPR);
        const unsigned* sr = srow + (size_t)row * CAPR;
        float acc0 = 0.f, acc1 = 0.f;
        for (int j0 = 0; j0 < cnt; j0 += 64) {
            unsigned ev = (j0 + lane < cnt) ? sr[j0 + lane] : 0u;
            int m = min(64, cnt - j0);
            int jj = 0;
            for (; jj + 1 < m; jj += 2) {
                unsigned e0 = __shfl(ev, jj);
                unsigned e1 = __shfl(ev, jj + 1);
                if (e0 & 1u) acc0 += en_emb[(size_t)(e0 >> 1) * 64 + lane];
                if (e1 & 1u) acc1 += en_emb[(size_t)(e1 >> 1) * 64 + lane];
            }
            if (jj < m) {
                unsigned e0 = __shfl(ev, jj);
                if (e0 & 1u) acc0 += en_emb[(size_t)(e0 >> 1) * 64 + lane];
            }
        }
        int uid = user_ids[row];
        float hval = 1.25f * (acc0 + acc1) + user_emb[(size_t)uid * 64 + lane] + en_off[lane];
        hb[(size_t)row * 64 + lane] = f2bf(tanhf(hval));
    } else {
        // ---- reg partial sums (atomic into zeroed reg_ws) ----
        const int bx = blockIdx.x - HBLK;
        const int stride = REGB * blockDim.x;
        float s = 0.f;
        for (int t = bx * blockDim.x + threadIdx.x; t < num_items * 16; t += stride) {
            int i = t >> 4, l = t & 15;
            if (mask[i]) {
                float4 e = *reinterpret_cast<const float4*>(en_emb + (size_t)i * 64 + l * 4);
                float4 d = *reinterpret_cast<const float4*>(de_emb + (size_t)i * 64 + l * 4);
                s += e.x*e.x + e.y*e.y + e.z*e.z + e.w*e.w
                   + d.x*d.x + d.y*d.y + d.z*d.z + d.w*d.w;
                if (l == 0) { float bb = de_bias[i]; s += bb * bb; }
            }
        }
        for (int t = bx * blockDim.x + threadIdx.x; t < B * 16; t += stride) {
            int b = t >> 4, l = t & 15;
            int uid = user_ids[b];
            float4 u = *reinterpret_cast<const float4*>(user_emb + (size_t)uid * 64 + l * 4);
            s += u.x*u.x + u.y*u.y + u.z*u.z + u.w*u.w;
        }
        if (bx == 0 && threadIdx.x < 64) {
            float o = en_off[threadIdx.x];
            s += o * o;
        }
        for (int m = 1; m < 64; m <<= 1) s += __shfl_xor(s, m);
        __shared__ float wsum[4];
        if ((threadIdx.x & 63) == 0) wsum[threadIdx.x >> 6] = s;
        __syncthreads();
        if (threadIdx.x == 0)
            atomicAdd(reg_ws, wsum[0] + wsum[1] + wsum[2] + wsum[3]);
    }
}

// ====== D3: ratings, 8-lane groups, uint4 bf16 loads, 4 chains, XCD-pinned ==
__global__ void k_ratings_bkt(const unsigned short* __restrict__ hb,
                              const unsigned short* __restrict__ debf,
                              const float* __restrict__ de_bias,
                              const unsigned* __restrict__ perm, const int* __restrict__ cursor,
                              float* __restrict__ r_perm) {
    const int bkt = blockIdx.x & (NB - 1);
    const int cnt = cursor[bkt];
    const int l = threadIdx.x & 7;                        // 8 lanes per pair
    const int gid = (blockIdx.x >> 3) * (blockDim.x >> 3) + (threadIdx.x >> 3);
    const int gpb = (gridDim.x >> 3) * (blockDim.x >> 3); // groups per bucket
    const unsigned* pb = perm + (size_t)bkt * CAPB;
    float* rb = r_perm + (size_t)bkt * CAPB;

    int slot = gid;
    for (; slot + 3 * gpb < cnt; slot += 4 * gpb) {       // 4 independent chains
        unsigned p0 = pb[slot];
        unsigned p1 = pb[slot + gpb];
        unsigned p2 = pb[slot + 2 * gpb];
        unsigned p3 = pb[slot + 3 * gpb];
        int it0 = (int)(p0 >> 12), b0 = (int)(p0 & 0xFFFu);
        int it1 = (int)(p1 >> 12), b1 = (int)(p1 & 0xFFFu);
        int it2 = (int)(p2 >> 12), b2 = (int)(p2 & 0xFFFu);
        int it3 = (int)(p3 >> 12), b3 = (int)(p3 & 0xFFFu);
        uint4 h0 = *reinterpret_cast<const uint4*>(hb   + (size_t)b0  * 64 + l * 8);
        uint4 d0 = *reinterpret_cast<const uint4*>(debf + (size_t)it0 * 64 + l * 8);
        uint4 h1 = *reinterpret_cast<const uint4*>(hb   + (size_t)b1  * 64 + l * 8);
        uint4 d1 = *reinterpret_cast<const uint4*>(debf + (size_t)it1 * 64 + l * 8);
        uint4 h2 = *reinterpret_cast<const uint4*>(hb   + (size_t)b2  * 64 + l * 8);
        uint4 d2 = *reinterpret_cast<const uint4*>(debf + (size_t)it2 * 64 + l * 8);
        uint4 h3 = *reinterpret_cast<const uint4*>(hb   + (size_t)b3  * 64 + l * 8);
        uint4 d3 = *reinterpret_cast<const uint4*>(debf + (size_t)it3 * 64 + l * 8);
        float s0 = bfdot8(h0, d0);
        float s1 = bfdot8(h1, d1);
        float s2 = bfdot8(h2, d2);
        float s3 = bfdot8(h3, d3);
        s0 += __shfl_xor(s0, 1); s1 += __shfl_xor(s1, 1);
        s2 += __shfl_xor(s2, 1); s3 += __shfl_xor(s3, 1);
        s0 += __shfl_xor(s0, 2); s1 += __shfl_xor(s1, 2);
        s2 += __shfl_xor(s2, 2); s3 += __shfl_xor(s3, 2);
        s0 += __shfl_xor(s0, 4); s1 += __shfl_xor(s1, 4);
        s2 += __shfl_xor(s2, 4); s3 += __shfl_xor(s3, 4);
        if (l == 0) {
            rb[slot]           = s0 + de_bias[it0];
            rb[slot + gpb]     = s1 + de_bias[it1];
            rb[slot + 2 * gpb] = s2 + de_bias[it2];
            rb[slot + 3 * gpb] = s3 + de_bias[it3];
        }
    }
    for (; slot < cnt; slot += gpb) {
        unsigned p = pb[slot];
        int item = (int)(p >> 12), bidx = (int)(p & 0xFFFu);
        uint4 hv = *reinterpret_cast<const uint4*>(hb   + (size_t)bidx * 64 + l * 8);
        uint4 dv = *reinterpret_cast<const uint4*>(debf + (size_t)item * 64 + l * 8);
        float s = bfdot8(hv, dv);
        s += __shfl_xor(s, 1);
        s += __shfl_xor(s, 2);
        s += __shfl_xor(s, 4);
        if (l == 0) rb[slot] = s + de_bias[item];
    }
}

// ============ D4: vectorized unpermute + reg finalize =======================
__global__ void k_unperm(const unsigned* __restrict__ inv, const float* __restrict__ r_perm,
                         const float* __restrict__ reg_ws, float* __restrict__ out, int N) {
    const int quads = N >> 2;
    const int stride = gridDim.x * blockDim.x;
    for (int q = blockIdx.x * blockDim.x + threadIdx.x; q < quads; q += stride) {
        uint4 iv = reinterpret_cast<const uint4*>(inv)[q];
        float4 o;
        o.x = r_perm[iv.x];
        o.y = r_perm[iv.y];
        o.z = r_perm[iv.z];
        o.w = r_perm[iv.w];
        reinterpret_cast<float4*>(out)[q] = o;
    }
    if (blockIdx.x == 0 && threadIdx.x == 0)
        out[N] = 0.5f * reg_ws[0];
}

// ===================== fallback (direct) path ===============================
__global__ void k_mask(const int* __restrict__ bat_items, unsigned char* __restrict__ mask,
                       int N) {
    int t = blockIdx.x * blockDim.x + threadIdx.x;
    if (t < N) mask[bat_items[t]] = 1;
}

__global__ void k_ratings(const float* __restrict__ hidden, const float* __restrict__ de_emb,
                          const float* __restrict__ de_bias,
                          const int* __restrict__ bat_idx, const int* __restrict__ bat_items,
                          float* __restrict__ out, int N) {
    const int l = threadIdx.x & 15;
    const int gid = (blockIdx.x * blockDim.x + threadIdx.x) >> 4;
    const int gstride = (gridDim.x * blockDim.x) >> 4;
    for (int n = gid; n < N; n += gstride) {
        int b  = bat_idx[n];
        int it = bat_items[n];
        float4 hv = *reinterpret_cast<const float4*>(hidden + (size_t)b  * 64 + l * 4);
        float4 dv = *reinterpret_cast<const float4*>(de_emb + (size_t)it * 64 + l * 4);
        float s = hv.x*dv.x + hv.y*dv.y + hv.z*dv.z + hv.w*dv.w;
        s += __shfl_xor(s, 1);
        s += __shfl_xor(s, 2);
        s += __shfl_xor(s, 4);
        s += __shfl_xor(s, 8);
        if (l == 0) out[n] = s + de_bias[it];
    }
}

__global__ void k_scatter(const int* __restrict__ sp_row, const int* __restrict__ sp_col,
                          const float* __restrict__ en_emb, float* __restrict__ hidden,
                          int nnz) {
    const int lane = threadIdx.x & 63;
    const int wave = (blockIdx.x * blockDim.x + threadIdx.x) >> 6;
    const int nwaves = (gridDim.x * blockDim.x) >> 6;
    for (int i = wave; i < nnz; i += nwaves) {
        if (!keep_mask(i, nnz)) continue;
        int row = sp_row[i];
        int col = sp_col[i];
        float v = 1.25f * en_emb[(size_t)col * 64 + lane];
        atomicAdd(&hidden[row * 64 + lane], v);
    }
}

__global__ void k_hfinish(float* __restrict__ hidden, const float* __restrict__ user_emb,
                          const int* __restrict__ user_ids, const float* __restrict__ en_off,
                          int B) {
    int t = blockIdx.x * blockDim.x + threadIdx.x;
    if (t >= B * 64) return;
    int b = t >> 6, d = t & 63;
    int uid = user_ids[b];
    float h = hidden[t] + user_emb[(size_t)uid * 64 + d] + en_off[d];
    hidden[t] = tanhf(h);
}

__global__ void k_reg_fb(const unsigned char* __restrict__ mask,
                         const float* __restrict__ en_emb, const float* __restrict__ de_emb,
                         const float* __restrict__ de_bias,
                         const float* __restrict__ user_emb, const int* __restrict__ user_ids,
                         const float* __restrict__ en_off,
                         float* __restrict__ reg, int num_items, int B) {
    const int stride = gridDim.x * blockDim.x;
    float s = 0.f;
    for (int t = blockIdx.x * blockDim.x + threadIdx.x; t < num_items * 16; t += stride) {
        int i = t >> 4, l = t & 15;
        if (mask[i]) {
            float4 e = *reinterpret_cast<const float4*>(en_emb + (size_t)i * 64 + l * 4);
            float4 d = *reinterpret_cast<const float4*>(de_emb + (size_t)i * 64 + l * 4);
            s += e.x*e.x + e.y*e.y + e.z*e.z + e.w*e.w
               + d.x*d.x + d.y*d.y + d.z*d.z + d.w*d.w;
            if (l == 0) { float bb = de_bias[i]; s += bb * bb; }
        }
    }
    for (int t = blockIdx.x * blockDim.x + threadIdx.x; t < B * 16; t += stride) {
        int b = t >> 4, l = t & 15;
        int uid = user_ids[b];
        float4 u = *reinterpret_cast<const float4*>(user_emb + (size_t)uid * 64 + l * 4);
        s += u.x*u.x + u.y*u.y + u.z*u.z + u.w*u.w;
    }
    if (blockIdx.x == 0 && threadIdx.x < 64) {
        float o = en_off[threadIdx.x];
        s += o * o;
    }
    for (int m = 1; m < 64; m <<= 1) s += __shfl_xor(s, m);
    __shared__ float wsum[4];
    if ((threadIdx.x & 63) == 0) wsum[threadIdx.x >> 6] = s;
    __syncthreads();
    if (threadIdx.x == 0)
        atomicAdd(reg, 0.5f * (wsum[0] + wsum[1] + wsum[2] + wsum[3]));
}

extern "C" void kernel_launch(void* const* d_in, const int* in_sizes, int n_in,
                              void* d_out, int out_size, void* d_ws, size_t ws_size,
                              hipStream_t stream) {
    const int*   user_ids  = (const int*)  d_in[0];
    const int*   bat_idx   = (const int*)  d_in[1];
    const int*   sp_row    = (const int*)  d_in[2];
    const int*   sp_col    = (const int*)  d_in[3];
    const int*   bat_items = (const int*)  d_in[4];
    const float* en_emb    = (const float*)d_in[5];
    const float* en_off    = (const float*)d_in[6];
    const float* de_emb    = (const float*)d_in[7];
    const float* de_bias   = (const float*)d_in[8];
    const float* user_emb  = (const float*)d_in[9];

    const int B         = in_sizes[0];
    const int N         = in_sizes[1];
    const int NNZ       = in_sizes[2];
    const int NUM_ITEMS = in_sizes[8];

    float* out = (float*)d_out;        // ratings [N]; reg scalar at out[N]

    // workspace: [mask | cursor | rowcur | reg_ws] one memset; rest no-init.
    char* ws = (char*)d_ws;
    size_t off = 0;
    unsigned char* mask = (unsigned char*)(ws + off);
    off += ((size_t)NUM_ITEMS + 255) & ~(size_t)255;
    int* cursor = (int*)(ws + off);               off += 256;
    int* rowcur = (int*)(ws + off);               off += (size_t)B * 4;
    float* reg_ws = (float*)(ws + off);           off += 256;
    const size_t zero_bytes = off;
    float* hidden = (float*)(ws + off);           off += (size_t)B * 64 * 4;  // fallback only
    unsigned* perm   = (unsigned*)(ws + off);     off += (size_t)NB * CAPB * 4;
    unsigned* inv    = (unsigned*)(ws + off);     off += (size_t)N * 4;
    float*    r_perm = (float*)(ws + off);
    unsigned* srow   = (unsigned*)r_perm;         // alias: disjoint lifetimes
    size_t tail = (size_t)NB * CAPB * 4;
    if ((size_t)B * CAPR * 4 > tail) tail = (size_t)B * CAPR * 4;
    off += tail;
    unsigned short* hb   = (unsigned short*)(ws + off);  off += (size_t)B * 64 * 2;
    off = (off + 15) & ~(size_t)15;
    unsigned short* debf = (unsigned short*)(ws + off);  off += (size_t)NUM_ITEMS * 64 * 2;

    const bool sorted_path =
        (ws_size >= off) && (N == (1 << 20)) && (B == 4096) &&
        (NUM_ITEMS <= (1 << 17)) && (NUM_ITEMS >= 65536) &&
        (NUM_ITEMS % 4 == 0) &&
        (NNZ % (RSB * 256) == 0) && (NNZ / RSB <= CAPR * 256);

    hipMemsetAsync(ws, 0, zero_bytes, stream);

    if (sorted_path) {
        k_prep<<<256 + RSB + CVTB, 256, 0, stream>>>(
            bat_idx, bat_items, mask, cursor, perm, inv,
            sp_row, sp_col, rowcur, srow, de_emb, debf, N, NUM_ITEMS, NNZ, B);
        k_hidden_reg<<<HBLK + REGB, 256, 0, stream>>>(
            srow, rowcur, en_emb, user_emb, user_ids, en_off, hb,
            mask, de_emb, de_bias, reg_ws, B, NUM_ITEMS);
        k_ratings_bkt<<<FATB, 256, 0, stream>>>(hb, debf, de_bias, perm, cursor, r_perm);
        k_unperm<<<1024, 256, 0, stream>>>(inv, r_perm, reg_ws, out, N);
    } else {
        hipMemsetAsync(hidden, 0, (size_t)B * 64 * 4, stream);
        hipMemsetAsync(out + N, 0, sizeof(float), stream);
        k_mask<<<(N + 255) / 256, 256, 0, stream>>>(bat_items, mask, N);
        k_scatter<<<FATB, 256, 0, stream>>>(sp_row, sp_col, en_emb, hidden, NNZ);
        k_hfinish<<<(B * 64 + 255) / 256, 256, 0, stream>>>(hidden, user_emb, user_ids,
                                                            en_off, B);
        k_ratings<<<FATB, 256, 0, stream>>>(hidden, de_emb, de_bias, bat_idx, bat_items, out, N);
        k_reg_fb<<<REGB, 256, 0, stream>>>(mask, en_emb, de_emb, de_bias,
                                           user_emb, user_ids, en_off, out + N, NUM_ITEMS, B);
    }
}

// Round 11
// 193.961 us; speedup vs baseline: 1.4729x; 1.0112x over previous
//
#include <hip/hip_runtime.h>
#include <hip/hip_bf16.h>

// ---------------------------------------------------------------------------
// CDAE forward. Round 11: fold de_emb cvt into the reg pass; hidden 4 chains.
// R10 post-mortem: 202.7->196.1us (matched ~195 prediction). Top-5 all
// harness 0xAA poison fills (3x~41us, 256MiB WRITE, 80-83% achievable HBM --
// those ARE at roofline, ~124us immovable). Ours ~72us vs ~50us floor.
// R11: D1's cvt branch re-reads de_emb (25.6MB) that D2's reg loop reads
// anyway -> emit debf ushort4 writes from the reg loop (unconditional; mask
// only gates the square-sum). Deletes 38MB from D1 (its dominant stream);
// D2 gains 12.8MB coalesced writes hidden under the hidden-branch gather
// latency (max-not-sum, R9-proven). Also k_hidden 2->4 gather chains.
// Predict 196 -> ~188-191us; if gain <3us => ROOFLINE.
// ---------------------------------------------------------------------------
#define PARTITIONABLE 1
#define NB 8               // item-slice buckets == XCDs (blockIdx&7 pinning)
#define CAPB 136192        // per-item-bucket capacity; E=131072, +14 sigma
#define FATB 2048          // fat grid size for ratings
#define CAPR 128           // per-row capacity; E=50
#define RSB 200            // rowsort blocks: NNZ=204800 = 200 * 4 * 256
#define HBLK 1024          // hidden blocks (B*64/256)
#define REGB 256           // reg partial blocks

__device__ __forceinline__ unsigned rotl32(unsigned x, int r) {
    return (x << r) | (x >> (32 - r));
}

__device__ __forceinline__ void threefry2x32(unsigned k0, unsigned k1,
                                             unsigned& x0, unsigned& x1) {
    unsigned ks0 = k0, ks1 = k1, ks2 = k0 ^ k1 ^ 0x1BD11BDAu;
    x0 += ks0; x1 += ks1;
#define TF_R(r) { x0 += x1; x1 = rotl32(x1, r); x1 ^= x0; }
    TF_R(13) TF_R(15) TF_R(26) TF_R(6)   x0 += ks1; x1 += ks2 + 1u;
    TF_R(17) TF_R(29) TF_R(16) TF_R(24)  x0 += ks2; x1 += ks0 + 2u;
    TF_R(13) TF_R(15) TF_R(26) TF_R(6)   x0 += ks0; x1 += ks1 + 3u;
    TF_R(17) TF_R(29) TF_R(16) TF_R(24)  x0 += ks1; x1 += ks2 + 4u;
    TF_R(13) TF_R(15) TF_R(26) TF_R(6)   x0 += ks2; x1 += ks0 + 5u;
#undef TF_R
}

__device__ __forceinline__ bool keep_mask(int i, int nnz) {
#if PARTITIONABLE
    unsigned x0 = 0u, x1 = (unsigned)i;
    threefry2x32(0u, 42u, x0, x1);
    unsigned bits = x0 ^ x1;
#else
    int half = nnz >> 1;
    int j = (i < half) ? i : i - half;
    unsigned x0 = (unsigned)j, x1 = (unsigned)(j + half);
    threefry2x32(0u, 42u, x0, x1);
    unsigned bits = (i < half) ? x0 : x1;
#endif
    float u = __uint_as_float((bits >> 9) | 0x3f800000u) - 1.0f;
    return u < 0.8f;
}

// fp32 -> bf16 round-to-nearest-even
__device__ __forceinline__ unsigned short f2bf(float f) {
    unsigned u = __float_as_uint(f);
    return (unsigned short)((u + 0x7FFFu + ((u >> 16) & 1u)) >> 16);
}

// dot of 8 bf16 pairs packed in uint4, fp32 accumulate
__device__ __forceinline__ float bfdot8(uint4 h, uint4 d) {
    float s;
    s  = __uint_as_float(h.x << 16)         * __uint_as_float(d.x << 16);
    s += __uint_as_float(h.x & 0xFFFF0000u) * __uint_as_float(d.x & 0xFFFF0000u);
    s += __uint_as_float(h.y << 16)         * __uint_as_float(d.y << 16);
    s += __uint_as_float(h.y & 0xFFFF0000u) * __uint_as_float(d.y & 0xFFFF0000u);
    s += __uint_as_float(h.z << 16)         * __uint_as_float(d.z << 16);
    s += __uint_as_float(h.z & 0xFFFF0000u) * __uint_as_float(d.z & 0xFFFF0000u);
    s += __uint_as_float(h.w << 16)         * __uint_as_float(d.w << 16);
    s += __uint_as_float(h.w & 0xFFFF0000u) * __uint_as_float(d.w & 0xFFFF0000u);
    return s;
}

// ============ D1: bucket (0..255) || rowsort (256..455) =====================
__global__ void k_prep(const int* __restrict__ bat_idx, const int* __restrict__ bat_items,
                       unsigned char* __restrict__ mask, int* __restrict__ cursor,
                       unsigned* __restrict__ perm, unsigned* __restrict__ inv,
                       const int* __restrict__ sp_row, const int* __restrict__ sp_col,
                       int* __restrict__ rowcur, unsigned* __restrict__ srow,
                       int N, int num_items, int nnz, int B) {
    __shared__ int sh[4096];                       // 16KB, shared by both branches
    if (blockIdx.x < 256) {
        // ---- pair bucketing by item slice ----
        if (threadIdx.x < NB) sh[threadIdx.x] = 0;
        __syncthreads();
        const int per = N / 256;                   // 4096
        const int base_n = blockIdx.x * per;
        const int iters = per / blockDim.x;        // 16
        unsigned packed[16];
        int bkt[16];
        for (int it = 0; it < iters; ++it) {
            int n = base_n + it * blockDim.x + threadIdx.x;
            int item = bat_items[n];
            int bidx = bat_idx[n];
            mask[item] = 1;
            int b = (int)(((unsigned long long)(unsigned)item * NB) / (unsigned)num_items);
            packed[it] = ((unsigned)item << 12) | (unsigned)bidx;   // item:17|bidx:12
            bkt[it] = b;
            atomicAdd(&sh[b], 1);
        }
        __syncthreads();
        if (threadIdx.x < NB) {
            int c = sh[threadIdx.x];
            sh[threadIdx.x] = atomicAdd(&cursor[threadIdx.x], c);
        }
        __syncthreads();
        for (int it = 0; it < iters; ++it) {
            int n = base_n + it * blockDim.x + threadIdx.x;
            int pos = atomicAdd(&sh[bkt[it]], 1);
            unsigned gpos = (unsigned)bkt[it] * CAPB + (unsigned)min(pos, CAPB - 1);
            perm[gpos] = packed[it];   // contiguous per-(block,bucket) runs
            inv[n] = gpos;             // coalesced
        }
    } else {
        // ---- nnz counting-sort by row; payload col<<1|keep ----
        const int blk = blockIdx.x - 256;
        for (int i = threadIdx.x; i < B; i += blockDim.x) sh[i] = 0;
        __syncthreads();
        const int per = nnz / RSB;                 // 1024
        const int base = blk * per;
        const int iters = per / blockDim.x;        // 4
        unsigned pk[8];
        int rw[8];
        for (int it = 0; it < iters; ++it) {
            int i = base + it * blockDim.x + threadIdx.x;
            int row = sp_row[i];
            int col = sp_col[i];
            unsigned k = keep_mask(i, nnz) ? 1u : 0u;
            pk[it] = ((unsigned)col << 1) | k;
            rw[it] = row;
            atomicAdd(&sh[row], 1);
        }
        __syncthreads();
        for (int i = threadIdx.x; i < B; i += blockDim.x) {
            int c = sh[i];
            if (c) sh[i] = atomicAdd(&rowcur[i], c);
        }
        __syncthreads();
        for (int it = 0; it < iters; ++it) {
            int pos = atomicAdd(&sh[rw[it]], 1);
            srow[(size_t)rw[it] * CAPR + min(pos, CAPR - 1)] = pk[it];
        }
    }
}

// ==== D2: hidden (0..1023) || reg partials + de_emb->bf16 (1024..1279) ======
__global__ void k_hidden_reg(const unsigned* __restrict__ srow, const int* __restrict__ rowcur,
                             const float* __restrict__ en_emb, const float* __restrict__ user_emb,
                             const int* __restrict__ user_ids, const float* __restrict__ en_off,
                             unsigned short* __restrict__ hb,
                             const unsigned char* __restrict__ mask,
                             const float* __restrict__ de_emb, const float* __restrict__ de_bias,
                             unsigned short* __restrict__ debf,
                             float* __restrict__ reg_ws, int B, int num_items) {
    if (blockIdx.x < HBLK) {
        // ---- hidden: one wave per row, 4 gather chains, bf16 store ----
        const int lane = threadIdx.x & 63;
        const int row = (blockIdx.x * blockDim.x + threadIdx.x) >> 6;
        if (row >= B) return;
        const int cnt = min(rowcur[row], CAPR);
        const unsigned* sr = srow + (size_t)row * CAPR;
        float acc0 = 0.f, acc1 = 0.f, acc2 = 0.f, acc3 = 0.f;
        for (int j0 = 0; j0 < cnt; j0 += 64) {
            unsigned ev = (j0 + lane < cnt) ? sr[j0 + lane] : 0u;
            int m = min(64, cnt - j0);
            int jj = 0;
            for (; jj + 3 < m; jj += 4) {           // 4 independent gather chains
                unsigned e0 = __shfl(ev, jj);
                unsigned e1 = __shfl(ev, jj + 1);
                unsigned e2 = __shfl(ev, jj + 2);
                unsigned e3 = __shfl(ev, jj + 3);
                if (e0 & 1u) acc0 += en_emb[(size_t)(e0 >> 1) * 64 + lane];
                if (e1 & 1u) acc1 += en_emb[(size_t)(e1 >> 1) * 64 + lane];
                if (e2 & 1u) acc2 += en_emb[(size_t)(e2 >> 1) * 64 + lane];
                if (e3 & 1u) acc3 += en_emb[(size_t)(e3 >> 1) * 64 + lane];
            }
            for (; jj < m; ++jj) {
                unsigned e0 = __shfl(ev, jj);
                if (e0 & 1u) acc0 += en_emb[(size_t)(e0 >> 1) * 64 + lane];
            }
        }
        int uid = user_ids[row];
        float hval = 1.25f * ((acc0 + acc1) + (acc2 + acc3))
                   + user_emb[(size_t)uid * 64 + lane] + en_off[lane];
        hb[(size_t)row * 64 + lane] = f2bf(tanhf(hval));
    } else {
        // ---- reg partials + de_emb fp32->bf16 cvt (reads de_emb once) ----
        const int bx = blockIdx.x - HBLK;
        const int stride = REGB * blockDim.x;
        float s = 0.f;
        for (int t = bx * blockDim.x + threadIdx.x; t < num_items * 16; t += stride) {
            int i = t >> 4, l = t & 15;
            float4 d = *reinterpret_cast<const float4*>(de_emb + (size_t)i * 64 + l * 4);
            ushort4 o;
            o.x = f2bf(d.x); o.y = f2bf(d.y); o.z = f2bf(d.z); o.w = f2bf(d.w);
            reinterpret_cast<ushort4*>(debf)[t] = o;   // t == i*16+l, coalesced
            if (mask[i]) {
                float4 e = *reinterpret_cast<const float4*>(en_emb + (size_t)i * 64 + l * 4);
                s += e.x*e.x + e.y*e.y + e.z*e.z + e.w*e.w
                   + d.x*d.x + d.y*d.y + d.z*d.z + d.w*d.w;
                if (l == 0) { float bb = de_bias[i]; s += bb * bb; }
            }
        }
        for (int t = bx * blockDim.x + threadIdx.x; t < B * 16; t += stride) {
            int b = t >> 4, l = t & 15;
            int uid = user_ids[b];
            float4 u = *reinterpret_cast<const float4*>(user_emb + (size_t)uid * 64 + l * 4);
            s += u.x*u.x + u.y*u.y + u.z*u.z + u.w*u.w;
        }
        if (bx == 0 && threadIdx.x < 64) {
            float o = en_off[threadIdx.x];
            s += o * o;
        }
        for (int m = 1; m < 64; m <<= 1) s += __shfl_xor(s, m);
        __shared__ float wsum[4];
        if ((threadIdx.x & 63) == 0) wsum[threadIdx.x >> 6] = s;
        __syncthreads();
        if (threadIdx.x == 0)
            atomicAdd(reg_ws, wsum[0] + wsum[1] + wsum[2] + wsum[3]);
    }
}

// ====== D3: ratings, 8-lane groups, uint4 bf16 loads, 4 chains, XCD-pinned ==
__global__ void k_ratings_bkt(const unsigned short* __restrict__ hb,
                              const unsigned short* __restrict__ debf,
                              const float* __restrict__ de_bias,
                              const unsigned* __restrict__ perm, const int* __restrict__ cursor,
                              float* __restrict__ r_perm) {
    const int bkt = blockIdx.x & (NB - 1);
    const int cnt = cursor[bkt];
    const int l = threadIdx.x & 7;                        // 8 lanes per pair
    const int gid = (blockIdx.x >> 3) * (blockDim.x >> 3) + (threadIdx.x >> 3);
    const int gpb = (gridDim.x >> 3) * (blockDim.x >> 3); // groups per bucket
    const unsigned* pb = perm + (size_t)bkt * CAPB;
    float* rb = r_perm + (size_t)bkt * CAPB;

    int slot = gid;
    for (; slot + 3 * gpb < cnt; slot += 4 * gpb) {       // 4 independent chains
        unsigned p0 = pb[slot];
        unsigned p1 = pb[slot + gpb];
        unsigned p2 = pb[slot + 2 * gpb];
        unsigned p3 = pb[slot + 3 * gpb];
        int it0 = (int)(p0 >> 12), b0 = (int)(p0 & 0xFFFu);
        int it1 = (int)(p1 >> 12), b1 = (int)(p1 & 0xFFFu);
        int it2 = (int)(p2 >> 12), b2 = (int)(p2 & 0xFFFu);
        int it3 = (int)(p3 >> 12), b3 = (int)(p3 & 0xFFFu);
        uint4 h0 = *reinterpret_cast<const uint4*>(hb   + (size_t)b0  * 64 + l * 8);
        uint4 d0 = *reinterpret_cast<const uint4*>(debf + (size_t)it0 * 64 + l * 8);
        uint4 h1 = *reinterpret_cast<const uint4*>(hb   + (size_t)b1  * 64 + l * 8);
        uint4 d1 = *reinterpret_cast<const uint4*>(debf + (size_t)it1 * 64 + l * 8);
        uint4 h2 = *reinterpret_cast<const uint4*>(hb   + (size_t)b2  * 64 + l * 8);
        uint4 d2 = *reinterpret_cast<const uint4*>(debf + (size_t)it2 * 64 + l * 8);
        uint4 h3 = *reinterpret_cast<const uint4*>(hb   + (size_t)b3  * 64 + l * 8);
        uint4 d3 = *reinterpret_cast<const uint4*>(debf + (size_t)it3 * 64 + l * 8);
        float s0 = bfdot8(h0, d0);
        float s1 = bfdot8(h1, d1);
        float s2 = bfdot8(h2, d2);
        float s3 = bfdot8(h3, d3);
        s0 += __shfl_xor(s0, 1); s1 += __shfl_xor(s1, 1);
        s2 += __shfl_xor(s2, 1); s3 += __shfl_xor(s3, 1);
        s0 += __shfl_xor(s0, 2); s1 += __shfl_xor(s1, 2);
        s2 += __shfl_xor(s2, 2); s3 += __shfl_xor(s3, 2);
        s0 += __shfl_xor(s0, 4); s1 += __shfl_xor(s1, 4);
        s2 += __shfl_xor(s2, 4); s3 += __shfl_xor(s3, 4);
        if (l == 0) {
            rb[slot]           = s0 + de_bias[it0];
            rb[slot + gpb]     = s1 + de_bias[it1];
            rb[slot + 2 * gpb] = s2 + de_bias[it2];
            rb[slot + 3 * gpb] = s3 + de_bias[it3];
        }
    }
    for (; slot < cnt; slot += gpb) {
        unsigned p = pb[slot];
        int item = (int)(p >> 12), bidx = (int)(p & 0xFFFu);
        uint4 hv = *reinterpret_cast<const uint4*>(hb   + (size_t)bidx * 64 + l * 8);
        uint4 dv = *reinterpret_cast<const uint4*>(debf + (size_t)item * 64 + l * 8);
        float s = bfdot8(hv, dv);
        s += __shfl_xor(s, 1);
        s += __shfl_xor(s, 2);
        s += __shfl_xor(s, 4);
        if (l == 0) rb[slot] = s + de_bias[item];
    }
}

// ============ D4: vectorized unpermute + reg finalize =======================
__global__ void k_unperm(const unsigned* __restrict__ inv, const float* __restrict__ r_perm,
                         const float* __restrict__ reg_ws, float* __restrict__ out, int N) {
    const int quads = N >> 2;
    const int stride = gridDim.x * blockDim.x;
    for (int q = blockIdx.x * blockDim.x + threadIdx.x; q < quads; q += stride) {
        uint4 iv = reinterpret_cast<const uint4*>(inv)[q];
        float4 o;
        o.x = r_perm[iv.x];
        o.y = r_perm[iv.y];
        o.z = r_perm[iv.z];
        o.w = r_perm[iv.w];
        reinterpret_cast<float4*>(out)[q] = o;
    }
    if (blockIdx.x == 0 && threadIdx.x == 0)
        out[N] = 0.5f * reg_ws[0];
}

// ===================== fallback (direct) path ===============================
__global__ void k_mask(const int* __restrict__ bat_items, unsigned char* __restrict__ mask,
                       int N) {
    int t = blockIdx.x * blockDim.x + threadIdx.x;
    if (t < N) mask[bat_items[t]] = 1;
}

__global__ void k_ratings(const float* __restrict__ hidden, const float* __restrict__ de_emb,
                          const float* __restrict__ de_bias,
                          const int* __restrict__ bat_idx, const int* __restrict__ bat_items,
                          float* __restrict__ out, int N) {
    const int l = threadIdx.x & 15;
    const int gid = (blockIdx.x * blockDim.x + threadIdx.x) >> 4;
    const int gstride = (gridDim.x * blockDim.x) >> 4;
    for (int n = gid; n < N; n += gstride) {
        int b  = bat_idx[n];
        int it = bat_items[n];
        float4 hv = *reinterpret_cast<const float4*>(hidden + (size_t)b  * 64 + l * 4);
        float4 dv = *reinterpret_cast<const float4*>(de_emb + (size_t)it * 64 + l * 4);
        float s = hv.x*dv.x + hv.y*dv.y + hv.z*dv.z + hv.w*dv.w;
        s += __shfl_xor(s, 1);
        s += __shfl_xor(s, 2);
        s += __shfl_xor(s, 4);
        s += __shfl_xor(s, 8);
        if (l == 0) out[n] = s + de_bias[it];
    }
}

__global__ void k_scatter(const int* __restrict__ sp_row, const int* __restrict__ sp_col,
                          const float* __restrict__ en_emb, float* __restrict__ hidden,
                          int nnz) {
    const int lane = threadIdx.x & 63;
    const int wave = (blockIdx.x * blockDim.x + threadIdx.x) >> 6;
    const int nwaves = (gridDim.x * blockDim.x) >> 6;
    for (int i = wave; i < nnz; i += nwaves) {
        if (!keep_mask(i, nnz)) continue;
        int row = sp_row[i];
        int col = sp_col[i];
        float v = 1.25f * en_emb[(size_t)col * 64 + lane];
        atomicAdd(&hidden[row * 64 + lane], v);
    }
}

__global__ void k_hfinish(float* __restrict__ hidden, const float* __restrict__ user_emb,
                          const int* __restrict__ user_ids, const float* __restrict__ en_off,
                          int B) {
    int t = blockIdx.x * blockDim.x + threadIdx.x;
    if (t >= B * 64) return;
    int b = t >> 6, d = t & 63;
    int uid = user_ids[b];
    float h = hidden[t] + user_emb[(size_t)uid * 64 + d] + en_off[d];
    hidden[t] = tanhf(h);
}

__global__ void k_reg_fb(const unsigned char* __restrict__ mask,
                         const float* __restrict__ en_emb, const float* __restrict__ de_emb,
                         const float* __restrict__ de_bias,
                         const float* __restrict__ user_emb, const int* __restrict__ user_ids,
                         const float* __restrict__ en_off,
                         float* __restrict__ reg, int num_items, int B) {
    const int stride = gridDim.x * blockDim.x;
    float s = 0.f;
    for (int t = blockIdx.x * blockDim.x + threadIdx.x; t < num_items * 16; t += stride) {
        int i = t >> 4, l = t & 15;
        if (mask[i]) {
            float4 e = *reinterpret_cast<const float4*>(en_emb + (size_t)i * 64 + l * 4);
            float4 d = *reinterpret_cast<const float4*>(de_emb + (size_t)i * 64 + l * 4);
            s += e.x*e.x + e.y*e.y + e.z*e.z + e.w*e.w
               + d.x*d.x + d.y*d.y + d.z*d.z + d.w*d.w;
            if (l == 0) { float bb = de_bias[i]; s += bb * bb; }
        }
    }
    for (int t = blockIdx.x * blockDim.x + threadIdx.x; t < B * 16; t += stride) {
        int b = t >> 4, l = t & 15;
        int uid = user_ids[b];
        float4 u = *reinterpret_cast<const float4*>(user_emb + (size_t)uid * 64 + l * 4);
        s += u.x*u.x + u.y*u.y + u.z*u.z + u.w*u.w;
    }
    if (blockIdx.x == 0 && threadIdx.x < 64) {
        float o = en_off[threadIdx.x];
        s += o * o;
    }
    for (int m = 1; m < 64; m <<= 1) s += __shfl_xor(s, m);
    __shared__ float wsum[4];
    if ((threadIdx.x & 63) == 0) wsum[threadIdx.x >> 6] = s;
    __syncthreads();
    if (threadIdx.x == 0)
        atomicAdd(reg, 0.5f * (wsum[0] + wsum[1] + wsum[2] + wsum[3]));
}

extern "C" void kernel_launch(void* const* d_in, const int* in_sizes, int n_in,
                              void* d_out, int out_size, void* d_ws, size_t ws_size,
                              hipStream_t stream) {
    const int*   user_ids  = (const int*)  d_in[0];
    const int*   bat_idx   = (const int*)  d_in[1];
    const int*   sp_row    = (const int*)  d_in[2];
    const int*   sp_col    = (const int*)  d_in[3];
    const int*   bat_items = (const int*)  d_in[4];
    const float* en_emb    = (const float*)d_in[5];
    const float* en_off    = (const float*)d_in[6];
    const float* de_emb    = (const float*)d_in[7];
    const float* de_bias   = (const float*)d_in[8];
    const float* user_emb  = (const float*)d_in[9];

    const int B         = in_sizes[0];
    const int N         = in_sizes[1];
    const int NNZ       = in_sizes[2];
    const int NUM_ITEMS = in_sizes[8];

    float* out = (float*)d_out;        // ratings [N]; reg scalar at out[N]

    // workspace: [mask | cursor | rowcur | reg_ws] one memset; rest no-init.
    char* ws = (char*)d_ws;
    size_t off = 0;
    unsigned char* mask = (unsigned char*)(ws + off);
    off += ((size_t)NUM_ITEMS + 255) & ~(size_t)255;
    int* cursor = (int*)(ws + off);               off += 256;
    int* rowcur = (int*)(ws + off);               off += (size_t)B * 4;
    float* reg_ws = (float*)(ws + off);           off += 256;
    const size_t zero_bytes = off;
    float* hidden = (float*)(ws + off);           off += (size_t)B * 64 * 4;  // fallback only
    unsigned* perm   = (unsigned*)(ws + off);     off += (size_t)NB * CAPB * 4;
    unsigned* inv    = (unsigned*)(ws + off);     off += (size_t)N * 4;
    float*    r_perm = (float*)(ws + off);
    unsigned* srow   = (unsigned*)r_perm;         // alias: disjoint lifetimes
    size_t tail = (size_t)NB * CAPB * 4;
    if ((size_t)B * CAPR * 4 > tail) tail = (size_t)B * CAPR * 4;
    off += tail;
    unsigned short* hb   = (unsigned short*)(ws + off);  off += (size_t)B * 64 * 2;
    off = (off + 15) & ~(size_t)15;
    unsigned short* debf = (unsigned short*)(ws + off);  off += (size_t)NUM_ITEMS * 64 * 2;

    const bool sorted_path =
        (ws_size >= off) && (N == (1 << 20)) && (B == 4096) &&
        (NUM_ITEMS <= (1 << 17)) && (NUM_ITEMS >= 65536) &&
        (NUM_ITEMS % 4 == 0) &&
        (NNZ % (RSB * 256) == 0) && (NNZ / RSB <= CAPR * 256);

    hipMemsetAsync(ws, 0, zero_bytes, stream);

    if (sorted_path) {
        k_prep<<<256 + RSB, 256, 0, stream>>>(
            bat_idx, bat_items, mask, cursor, perm, inv,
            sp_row, sp_col, rowcur, srow, N, NUM_ITEMS, NNZ, B);
        k_hidden_reg<<<HBLK + REGB, 256, 0, stream>>>(
            srow, rowcur, en_emb, user_emb, user_ids, en_off, hb,
            mask, de_emb, de_bias, debf, reg_ws, B, NUM_ITEMS);
        k_ratings_bkt<<<FATB, 256, 0, stream>>>(hb, debf, de_bias, perm, cursor, r_perm);
        k_unperm<<<1024, 256, 0, stream>>>(inv, r_perm, reg_ws, out, N);
    } else {
        hipMemsetAsync(hidden, 0, (size_t)B * 64 * 4, stream);
        hipMemsetAsync(out + N, 0, sizeof(float), stream);
        k_mask<<<(N + 255) / 256, 256, 0, stream>>>(bat_items, mask, N);
        k_scatter<<<FATB, 256, 0, stream>>>(sp_row, sp_col, en_emb, hidden, NNZ);
        k_hfinish<<<(B * 64 + 255) / 256, 256, 0, stream>>>(hidden, user_emb, user_ids,
                                                            en_off, B);
        k_ratings<<<FATB, 256, 0, stream>>>(hidden, de_emb, de_bias, bat_idx, bat_items, out, N);
        k_reg_fb<<<REGB, 256, 0, stream>>>(mask, en_emb, de_emb, de_bias,
                                           user_emb, user_ids, en_off, out + N, NUM_ITEMS, B);
    }
}